// Round 4
// baseline (1806.317 us; speedup 1.0000x reference)
//
#include <hip/hip_runtime.h>
#include <hip/hip_bf16.h>

// Problem constants. Established by rounds 0-3:
//   - inputs are fp32 (reading as bf16 -> NaN; round 2)
//   - OUTPUT is fp32 (writing bf16 -> stable absmax ~4.05 from pair-decode; rounds 1,3)
// Detector kept as cheap insurance for the input dtype.
#define B_  2
#define T_  2048
#define D_  1024
#define H_  16
#define DH_ 64
#define R_  32
#define BT_ (B_*T_)          // 4096
#define N1_ 2048             // gemm1 cols: 512 ql + 512 kl + 1024 v

typedef unsigned short u16;
typedef unsigned int   u32;

// Workspace layout (float elements). Total = 14,680,128 f = 58.7 MB.
#define OFF_FLAG 0                          // int flag (64 floats reserved)
#define OFF_WCAT 64                         // (D, 2048) = [Wql | Wkl | Wv]
#define SZ_WCAT  (D_*2048)                  // 2,097,152
#define OFF_QL   (OFF_WCAT + SZ_WCAT)
#define SZ_L     (B_*H_*T_*R_)              // 2,097,152
#define OFF_KL   (OFF_QL + SZ_L)
#define OFF_V    (OFF_KL + SZ_L)
#define SZ_V     (B_*H_*T_*DH_)             // 4,194,304
#define OFF_Y    (OFF_V + SZ_V)             // y: (B,T,D) fp32

#define NEG_ -1.0e30f

__device__ __forceinline__ float bfs(u16 s) {
    union { u32 i; float f; } w; w.i = ((u32)s) << 16; return w.f;
}
__device__ __forceinline__ float bflo(u32 u) {
    union { u32 i; float f; } w; w.i = u << 16; return w.f;
}
__device__ __forceinline__ float bfhi(u32 u) {
    union { u32 i; float f; } w; w.i = u & 0xFFFF0000u; return w.f;
}

// ---------------------------------------------------------------------------
// Kernel D: detect input dtype (1 = bf16, 0 = fp32). bf16 data: low 16 bits of
// each u32 word are a bf16 of ~N(0,1) -> exponent in [100,150] ~always. fp32
// data: low 16 bits are uniform mantissa bits -> ~20% band hits.
// ---------------------------------------------------------------------------
__global__ __launch_bounds__(64) void detect_dtype(const u32* __restrict__ xw,
                                                   int* __restrict__ flag)
{
    const int tid = threadIdx.x;
    int hits = 0;
    for (int i = tid; i < 512; i += 64) {
        const u32 w = xw[i];
        const u32 h = w & 0xFFFFu;
        const u32 e = (h >> 7) & 0xFFu;
        if (h == 0u || (e >= 100u && e <= 150u)) ++hits;
    }
    #pragma unroll
    for (int off = 32; off; off >>= 1) hits += __shfl_down(hits, off, 64);
    if (tid == 0) *flag = (hits >= 300) ? 1 : 0;
}

// ---------------------------------------------------------------------------
// Kernel 0a: fold LSR weights (+ core + 1/sqrt(R)) into the QKV projection.
// Wcat[d][h*R+r]       = sum_dh Wqkv[d][h*64+dh]     * Wq_lsr[h][dh][r] * core[h][r] / sqrt(R)
// Wcat[d][512 + h*R+r] = sum_dh Wqkv[d][D + h*64+dh] * Wk_lsr[h][dh][r]
// ---------------------------------------------------------------------------
__global__ __launch_bounds__(256) void fold_weights(
    const void* __restrict__ Wqkv, const void* __restrict__ Wq_lsr,
    const void* __restrict__ Wk_lsr, const void* __restrict__ core,
    float* __restrict__ Wcat, const int* __restrict__ flag)
{
    const int isbf = *flag;
    const int idx = blockIdx.x * 256 + threadIdx.x;   // over D_*512 = 524288
    const int d  = idx >> 9;
    const int hr = idx & 511;
    const int h  = hr >> 5;
    const int r  = hr & 31;
    float sq = 0.f, sk = 0.f, c;
    if (isbf) {
        const u16* W  = (const u16*)Wqkv;
        const u16* Aq = (const u16*)Wq_lsr;
        const u16* Ak = (const u16*)Wk_lsr;
        #pragma unroll
        for (int dh = 0; dh < DH_; ++dh) {
            const int wi = d * (3*D_) + h * DH_ + dh;
            const int ai = (h * DH_ + dh) * R_ + r;
            sq = fmaf(bfs(W[wi]),      bfs(Aq[ai]), sq);
            sk = fmaf(bfs(W[wi + D_]), bfs(Ak[ai]), sk);
        }
        c = bfs(((const u16*)core)[h * R_ + r]);
    } else {
        const float* W  = (const float*)Wqkv;
        const float* Aq = (const float*)Wq_lsr;
        const float* Ak = (const float*)Wk_lsr;
        #pragma unroll
        for (int dh = 0; dh < DH_; ++dh) {
            const int wi = d * (3*D_) + h * DH_ + dh;
            const int ai = (h * DH_ + dh) * R_ + r;
            sq = fmaf(W[wi],      Aq[ai], sq);
            sk = fmaf(W[wi + D_], Ak[ai], sk);
        }
        c = ((const float*)core)[h * R_ + r];
    }
    const float scale = 0.17677669529663687f;  // 1/sqrt(32)
    Wcat[d * 2048 + hr]       = sq * c * scale;
    Wcat[d * 2048 + 512 + hr] = sk;
}

// Kernel 0b: copy V slice of Wqkv into Wcat cols 1024..2047 (fp32)
__global__ __launch_bounds__(256) void convert_wv(
    const void* __restrict__ Wqkv, float* __restrict__ Wcat,
    const int* __restrict__ flag)
{
    const int isbf = *flag;
    const int idx = blockIdx.x * 256 + threadIdx.x;   // over D_*D_ = 1048576
    const int d = idx >> 10;
    const int c = idx & 1023;
    const int src = d * (3*D_) + 2*D_ + c;
    Wcat[d * 2048 + 1024 + c] =
        isbf ? bfs(((const u16*)Wqkv)[src]) : ((const float*)Wqkv)[src];
}

// ---------------------------------------------------------------------------
// Kernel 1: gemm1  x(4096,1024) @ Wcat_f32(1024,2048), fp32 accum.
// 128x128 tile, 256 threads, 8x8 micro-tile, BK=16.
// Epilogue scatters fp32 into ql/kl (B,H,T,R) and v (B,H,T,DH).
// ---------------------------------------------------------------------------
__global__ __launch_bounds__(256) void fused_qkv_lsr_gemm(
    const void* __restrict__ x, const float* __restrict__ Wcat,
    float* __restrict__ ql, float* __restrict__ kl, float* __restrict__ v,
    const int* __restrict__ flag)
{
    __shared__ float As[16][132];   // [k][m]
    __shared__ float Bs[16][132];   // [k][n]
    const int isbf = *flag;
    const int tid = threadIdx.x;
    const int bm  = blockIdx.y * 128;
    const int bn  = blockIdx.x * 128;

    const int a_m = tid >> 1;            // 0..127
    const int a_k = (tid & 1) * 8;       // 0 or 8
    const int b_k = tid >> 4;            // 0..15
    const int b_n = (tid & 15) * 8;      // 0..120
    const int tx  = tid & 15;
    const int ty  = tid >> 4;

    float acc[8][8];
    #pragma unroll
    for (int i = 0; i < 8; ++i)
        #pragma unroll
        for (int j = 0; j < 8; ++j) acc[i][j] = 0.f;

    for (int kt = 0; kt < D_; kt += 16) {
        float av[8];
        if (isbf) {
            uint4 xv = *(const uint4*)((const u16*)x + (bm + a_m) * D_ + kt + a_k);
            av[0]=bflo(xv.x); av[1]=bfhi(xv.x); av[2]=bflo(xv.y); av[3]=bfhi(xv.y);
            av[4]=bflo(xv.z); av[5]=bfhi(xv.z); av[6]=bflo(xv.w); av[7]=bfhi(xv.w);
        } else {
            float4 a0 = *(const float4*)((const float*)x + (bm + a_m) * D_ + kt + a_k);
            float4 a1 = *(const float4*)((const float*)x + (bm + a_m) * D_ + kt + a_k + 4);
            av[0]=a0.x; av[1]=a0.y; av[2]=a0.z; av[3]=a0.w;
            av[4]=a1.x; av[5]=a1.y; av[6]=a1.z; av[7]=a1.w;
        }
        float4 bv0 = *(const float4*)(Wcat + (kt + b_k) * 2048 + bn + b_n);
        float4 bv1 = *(const float4*)(Wcat + (kt + b_k) * 2048 + bn + b_n + 4);
        #pragma unroll
        for (int q = 0; q < 8; ++q) As[a_k + q][a_m] = av[q];
        *(float4*)&Bs[b_k][b_n]     = bv0;
        *(float4*)&Bs[b_k][b_n + 4] = bv1;
        __syncthreads();
        #pragma unroll
        for (int kk = 0; kk < 16; ++kk) {
            float a[8], b[8];
            #pragma unroll
            for (int i = 0; i < 4; ++i) { a[i] = As[kk][ty*4 + i]; a[4+i] = As[kk][64 + ty*4 + i]; }
            #pragma unroll
            for (int j = 0; j < 4; ++j) { b[j] = Bs[kk][tx*4 + j]; b[4+j] = Bs[kk][64 + tx*4 + j]; }
            #pragma unroll
            for (int i = 0; i < 8; ++i)
                #pragma unroll
                for (int j = 0; j < 8; ++j)
                    acc[i][j] = fmaf(a[i], b[j], acc[i][j]);
        }
        __syncthreads();
    }

    #pragma unroll
    for (int ri = 0; ri < 2; ++ri) {
        #pragma unroll
        for (int i = 0; i < 4; ++i) {
            const int row = bm + ri*64 + ty*4 + i;
            const int b   = row >> 11;          // /T_
            const int t   = row & (T_ - 1);
            #pragma unroll
            for (int rj = 0; rj < 2; ++rj) {
                #pragma unroll
                for (int j = 0; j < 4; ++j) {
                    const int col = bn + rj*64 + tx*4 + j;
                    const float val = acc[ri*4 + i][rj*4 + j];
                    if (col < 512) {
                        const int h = col >> 5, r = col & 31;
                        ql[((b*H_ + h)*T_ + t)*R_ + r] = val;
                    } else if (col < 1024) {
                        const int c = col - 512; const int h = c >> 5, r = c & 31;
                        kl[((b*H_ + h)*T_ + t)*R_ + r] = val;
                    } else {
                        const int c = col - 1024; const int h = c >> 6, dh = c & 63;
                        v[((b*H_ + h)*T_ + t)*DH_ + dh] = val;
                    }
                }
            }
        }
    }
}

// ---------------------------------------------------------------------------
// Kernel 2: flash-style causal attention over the low-rank scores (all fp32).
// One block per (bh, q-tile of 64 rows). 256 threads. No infinities (NEG_).
// ---------------------------------------------------------------------------
__global__ __launch_bounds__(256) void attn_kernel(
    const float* __restrict__ ql, const float* __restrict__ kl,
    const float* __restrict__ v, float* __restrict__ y)
{
    __shared__ float qls[64][R_ + 1];
    __shared__ float kls[64][R_ + 1];
    __shared__ float vs[64][DH_];
    __shared__ float sc[64][65];
    __shared__ float alpha_s[64];
    __shared__ float l_s[64];

    const int tid = threadIdx.x;
    const int qt  = blockIdx.x;        // 0..31
    const int bh  = blockIdx.y;        // 0..31
    const int t0  = qt * 64;

    for (int e = tid; e < 64 * R_; e += 256)
        qls[e >> 5][e & 31] = ql[(bh * T_ + t0) * R_ + e];

    float m_r = NEG_, l_r = 0.f;       // valid for tid<64 (row = tid)
    float acc[16];
    #pragma unroll
    for (int i = 0; i < 16; ++i) acc[i] = 0.f;
    const int tx = tid & 63;           // output col (dh)
    const int ty = tid >> 6;           // row group 0..3

    for (int s0 = 0; s0 <= t0; s0 += 64) {
        __syncthreads();  // protect kls/vs/sc from previous iteration
        for (int e = tid; e < 64 * R_; e += 256)
            kls[e >> 5][e & 31] = kl[(bh * T_ + s0) * R_ + e];
        {
            const float4* src = (const float4*)(v + (bh * T_ + s0) * DH_);  // 1024 float4
            float4* dst = (float4*)&vs[0][0];
            for (int e = tid; e < 1024; e += 256) dst[e] = src[e];
        }
        __syncthreads();

        // phase 1: scores
        {
            const int s  = tid & 63;
            const int tb = (tid >> 6) * 16;
            #pragma unroll
            for (int i = 0; i < 16; ++i) {
                const int t = tb + i;
                float sa = 0.f;
                #pragma unroll
                for (int r = 0; r < R_; ++r) sa = fmaf(qls[t][r], kls[s][r], sa);
                sc[t][s] = (s0 + s <= t0 + t) ? sa : NEG_;
            }
        }
        __syncthreads();

        // phase 2: online softmax (wave 0; row = tid). s=0 is always unmasked,
        // so rmax is a real score.
        if (tid < 64) {
            float rmax = NEG_;
            #pragma unroll
            for (int s = 0; s < 64; ++s) rmax = fmaxf(rmax, sc[tid][s]);
            const float nm = fmaxf(m_r, rmax);
            const float a  = __expf(m_r - nm);   // first tile: exp(-1e30) -> 0
            float sum = 0.f;
            #pragma unroll
            for (int s = 0; s < 64; ++s) {
                const float p = __expf(sc[tid][s] - nm);  // masked -> 0
                sc[tid][s] = p;
                sum += p;
            }
            m_r = nm;
            l_r = l_r * a + sum;
            alpha_s[tid] = a;
        }
        __syncthreads();

        // phase 3: rescale + P@V
        #pragma unroll
        for (int i = 0; i < 16; ++i) {
            const int t = ty * 16 + i;
            const float a = alpha_s[t];
            float sa = 0.f;
            #pragma unroll
            for (int s = 0; s < 64; ++s) sa = fmaf(sc[t][s], vs[s][tx], sa);
            acc[i] = acc[i] * a + sa;
        }
    }

    if (tid < 64) l_s[tid] = l_r;
    __syncthreads();

    const int b = bh >> 4, h = bh & 15;
    #pragma unroll
    for (int i = 0; i < 16; ++i) {
        const int t = ty * 16 + i;
        y[(b * T_ + t0 + t) * D_ + h * DH_ + tx] = acc[i] / l_s[t];
    }
}

// ---------------------------------------------------------------------------
// Kernel 3: out = y_f32(4096,1024) @ Wo(1024,1024), FP32 store.
// 64x64 tile, 256 threads, 4x4 micro-tile, BK=16.
// ---------------------------------------------------------------------------
__global__ __launch_bounds__(256) void out_gemm(
    const float* __restrict__ y, const void* __restrict__ Wo,
    float* __restrict__ out, const int* __restrict__ flag)
{
    __shared__ float As[16][68];
    __shared__ float Bs[16][68];
    const int isbf = *flag;
    const int tid = threadIdx.x;
    const int bm  = blockIdx.y * 64;
    const int bn  = blockIdx.x * 64;
    const int a_m = tid >> 2;          // 0..63
    const int a_k = (tid & 3) << 2;    // 0,4,8,12
    const int b_k = tid >> 4;          // 0..15
    const int b_n = (tid & 15) << 2;   // 0..60
    const int tx  = tid & 15;
    const int ty  = tid >> 4;
    float acc[4][4];
    #pragma unroll
    for (int i = 0; i < 4; ++i)
        #pragma unroll
        for (int j = 0; j < 4; ++j) acc[i][j] = 0.f;

    for (int kt = 0; kt < D_; kt += 16) {
        float4 av = *(const float4*)(y + (bm + a_m) * D_ + kt + a_k);
        As[a_k+0][a_m] = av.x; As[a_k+1][a_m] = av.y;
        As[a_k+2][a_m] = av.z; As[a_k+3][a_m] = av.w;
        if (isbf) {
            uint2 bw = *(const uint2*)((const u16*)Wo + (kt + b_k) * D_ + bn + b_n);
            Bs[b_k][b_n+0] = bflo(bw.x); Bs[b_k][b_n+1] = bfhi(bw.x);
            Bs[b_k][b_n+2] = bflo(bw.y); Bs[b_k][b_n+3] = bfhi(bw.y);
        } else {
            float4 bv = *(const float4*)((const float*)Wo + (kt + b_k) * D_ + bn + b_n);
            Bs[b_k][b_n+0] = bv.x; Bs[b_k][b_n+1] = bv.y;
            Bs[b_k][b_n+2] = bv.z; Bs[b_k][b_n+3] = bv.w;
        }
        __syncthreads();
        #pragma unroll
        for (int kk = 0; kk < 16; ++kk) {
            float a[4], b[4];
            #pragma unroll
            for (int i = 0; i < 4; ++i) a[i] = As[kk][ty*4 + i];
            #pragma unroll
            for (int j = 0; j < 4; ++j) b[j] = Bs[kk][tx*4 + j];
            #pragma unroll
            for (int i = 0; i < 4; ++i)
                #pragma unroll
                for (int j = 0; j < 4; ++j)
                    acc[i][j] = fmaf(a[i], b[j], acc[i][j]);
        }
        __syncthreads();
    }
    #pragma unroll
    for (int i = 0; i < 4; ++i) {
        const int row = bm + ty*4 + i;
        #pragma unroll
        for (int j = 0; j < 4; ++j)
            out[row * D_ + bn + tx*4 + j] = acc[i][j];
    }
}

// ---------------------------------------------------------------------------
extern "C" void kernel_launch(void* const* d_in, const int* in_sizes, int n_in,
                              void* d_out, int out_size, void* d_ws, size_t ws_size,
                              hipStream_t stream)
{
    (void)out_size; (void)ws_size;
    // Identify inputs by element count (unique except the two 32K LSR tensors,
    // which keep dict order among themselves). Fallback: dict order.
    const void* in_x = nullptr; const void* in_wqkv = nullptr;
    const void* in_wq = nullptr; const void* in_wk = nullptr;
    const void* in_core = nullptr; const void* in_wo = nullptr;
    for (int i = 0; i < n_in; ++i) {
        const int s = in_sizes[i];
        if      (s == BT_*D_)     { if (!in_x)    in_x    = d_in[i]; }
        else if (s == D_*3*D_)    { if (!in_wqkv) in_wqkv = d_in[i]; }
        else if (s == H_*DH_*R_)  { if (!in_wq)   in_wq   = d_in[i]; else if (!in_wk) in_wk = d_in[i]; }
        else if (s == H_*R_)      { if (!in_core) in_core = d_in[i]; }
        else if (s == D_*D_)      { if (!in_wo)   in_wo   = d_in[i]; }
    }
    if (!in_x)    in_x    = d_in[0];
    if (!in_wqkv) in_wqkv = d_in[1];
    if (!in_wq)   in_wq   = d_in[2];
    if (!in_wk)   in_wk   = d_in[3];
    if (!in_core) in_core = d_in[4];
    if (!in_wo)   in_wo   = d_in[5];

    float* out = (float*)d_out;   // reference output dtype is float32

    float* ws   = (float*)d_ws;
    int*   flag = (int*)(ws + OFF_FLAG);
    float* Wcat = ws + OFF_WCAT;
    float* ql   = ws + OFF_QL;
    float* kl   = ws + OFF_KL;
    float* v    = ws + OFF_V;
    float* y    = ws + OFF_Y;

    detect_dtype<<<1, 64, 0, stream>>>((const u32*)in_x, flag);
    fold_weights<<<(D_*512)/256, 256, 0, stream>>>(in_wqkv, in_wq, in_wk, in_core, Wcat, flag);
    convert_wv<<<(D_*D_)/256, 256, 0, stream>>>(in_wqkv, Wcat, flag);
    fused_qkv_lsr_gemm<<<dim3(N1_/128, BT_/128), 256, 0, stream>>>(in_x, Wcat, ql, kl, v, flag);
    attn_kernel<<<dim3(T_/64, B_*H_), 256, 0, stream>>>(ql, kl, v, y);
    out_gemm<<<dim3(D_/64, BT_/64), 256, 0, stream>>>(y, in_wo, out, flag);
}

// Round 5
// 1077.824 us; speedup vs baseline: 1.6759x; 1.6759x over previous
//
#include <hip/hip_runtime.h>
#include <hip/hip_bf16.h>

// Problem constants. Established by rounds 0-4:
//   - inputs fp32 (bf16 reinterpret -> NaN), output fp32, passing at absmax 2e-3.
#define B_  2
#define T_  2048
#define D_  1024
#define H_  16
#define DH_ 64
#define R_  32
#define BT_ (B_*T_)          // 4096
#define N1_ 2048             // gemm1 cols: 512 ql + 512 kl + 1024 v

typedef unsigned short u16;
typedef unsigned int   u32;

// Workspace layout (float elements). Total = 14,680,128 f = 58.7 MB.
#define OFF_FLAG 0                          // int flag (64 floats reserved)
#define OFF_WCAT 64                         // (D, 2048) = [Wql | Wkl | Wv]
#define SZ_WCAT  (D_*2048)
#define OFF_QL   (OFF_WCAT + SZ_WCAT)
#define SZ_L     (B_*H_*T_*R_)
#define OFF_KL   (OFF_QL + SZ_L)
#define OFF_V    (OFF_KL + SZ_L)
#define SZ_V     (B_*H_*T_*DH_)
#define OFF_Y    (OFF_V + SZ_V)

#define NEG_ -1.0e30f

__device__ __forceinline__ float bfs(u16 s) {
    union { u32 i; float f; } w; w.i = ((u32)s) << 16; return w.f;
}
__device__ __forceinline__ float bflo(u32 u) {
    union { u32 i; float f; } w; w.i = u << 16; return w.f;
}
__device__ __forceinline__ float bfhi(u32 u) {
    union { u32 i; float f; } w; w.i = u & 0xFFFF0000u; return w.f;
}

// ---------------------------------------------------------------------------
// Kernel D: detect input dtype (1 = bf16, 0 = fp32) — insurance only.
// ---------------------------------------------------------------------------
__global__ __launch_bounds__(64) void detect_dtype(const u32* __restrict__ xw,
                                                   int* __restrict__ flag)
{
    const int tid = threadIdx.x;
    int hits = 0;
    for (int i = tid; i < 512; i += 64) {
        const u32 w = xw[i];
        const u32 h = w & 0xFFFFu;
        const u32 e = (h >> 7) & 0xFFu;
        if (h == 0u || (e >= 100u && e <= 150u)) ++hits;
    }
    #pragma unroll
    for (int off = 32; off; off >>= 1) hits += __shfl_down(hits, off, 64);
    if (tid == 0) *flag = (hits >= 300) ? 1 : 0;
}

// ---------------------------------------------------------------------------
// Kernel 0a: fold LSR weights (+ core + 1/sqrt(R)) into the QKV projection.
// ---------------------------------------------------------------------------
__global__ __launch_bounds__(256) void fold_weights(
    const void* __restrict__ Wqkv, const void* __restrict__ Wq_lsr,
    const void* __restrict__ Wk_lsr, const void* __restrict__ core,
    float* __restrict__ Wcat, const int* __restrict__ flag)
{
    const int isbf = *flag;
    const int idx = blockIdx.x * 256 + threadIdx.x;   // over D_*512
    const int d  = idx >> 9;
    const int hr = idx & 511;
    const int h  = hr >> 5;
    const int r  = hr & 31;
    float sq = 0.f, sk = 0.f, c;
    if (isbf) {
        const u16* W  = (const u16*)Wqkv;
        const u16* Aq = (const u16*)Wq_lsr;
        const u16* Ak = (const u16*)Wk_lsr;
        #pragma unroll
        for (int dh = 0; dh < DH_; ++dh) {
            const int wi = d * (3*D_) + h * DH_ + dh;
            const int ai = (h * DH_ + dh) * R_ + r;
            sq = fmaf(bfs(W[wi]),      bfs(Aq[ai]), sq);
            sk = fmaf(bfs(W[wi + D_]), bfs(Ak[ai]), sk);
        }
        c = bfs(((const u16*)core)[h * R_ + r]);
    } else {
        const float* W  = (const float*)Wqkv;
        const float* Aq = (const float*)Wq_lsr;
        const float* Ak = (const float*)Wk_lsr;
        #pragma unroll
        for (int dh = 0; dh < DH_; ++dh) {
            const int wi = d * (3*D_) + h * DH_ + dh;
            const int ai = (h * DH_ + dh) * R_ + r;
            sq = fmaf(W[wi],      Aq[ai], sq);
            sk = fmaf(W[wi + D_], Ak[ai], sk);
        }
        c = ((const float*)core)[h * R_ + r];
    }
    const float scale = 0.17677669529663687f;  // 1/sqrt(32)
    Wcat[d * 2048 + hr]       = sq * c * scale;
    Wcat[d * 2048 + 512 + hr] = sk;
}

// Kernel 0b: copy V slice of Wqkv into Wcat cols 1024..2047 (fp32)
__global__ __launch_bounds__(256) void convert_wv(
    const void* __restrict__ Wqkv, float* __restrict__ Wcat,
    const int* __restrict__ flag)
{
    const int isbf = *flag;
    const int idx = blockIdx.x * 256 + threadIdx.x;   // over D_*D_
    const int d = idx >> 10;
    const int c = idx & 1023;
    const int src = d * (3*D_) + 2*D_ + c;
    Wcat[d * 2048 + 1024 + c] =
        isbf ? bfs(((const u16*)Wqkv)[src]) : ((const float*)Wqkv)[src];
}

// ---------------------------------------------------------------------------
// Kernel 1: gemm1  x(4096,1024) @ Wcat_f32(1024,2048), fp32 accum.
// 128x128 tile, 256 threads, 8x8 micro-tile, BK=16. Scattered epilogue.
// ---------------------------------------------------------------------------
__global__ __launch_bounds__(256) void fused_qkv_lsr_gemm(
    const void* __restrict__ x, const float* __restrict__ Wcat,
    float* __restrict__ ql, float* __restrict__ kl, float* __restrict__ v,
    const int* __restrict__ flag)
{
    __shared__ float As[16][132];
    __shared__ float Bs[16][132];
    const int isbf = *flag;
    const int tid = threadIdx.x;
    const int bm  = blockIdx.y * 128;
    const int bn  = blockIdx.x * 128;

    const int a_m = tid >> 1;
    const int a_k = (tid & 1) * 8;
    const int b_k = tid >> 4;
    const int b_n = (tid & 15) * 8;
    const int tx  = tid & 15;
    const int ty  = tid >> 4;

    float acc[8][8];
    #pragma unroll
    for (int i = 0; i < 8; ++i)
        #pragma unroll
        for (int j = 0; j < 8; ++j) acc[i][j] = 0.f;

    for (int kt = 0; kt < D_; kt += 16) {
        float av[8];
        if (isbf) {
            uint4 xv = *(const uint4*)((const u16*)x + (bm + a_m) * D_ + kt + a_k);
            av[0]=bflo(xv.x); av[1]=bfhi(xv.x); av[2]=bflo(xv.y); av[3]=bfhi(xv.y);
            av[4]=bflo(xv.z); av[5]=bfhi(xv.z); av[6]=bflo(xv.w); av[7]=bfhi(xv.w);
        } else {
            float4 a0 = *(const float4*)((const float*)x + (bm + a_m) * D_ + kt + a_k);
            float4 a1 = *(const float4*)((const float*)x + (bm + a_m) * D_ + kt + a_k + 4);
            av[0]=a0.x; av[1]=a0.y; av[2]=a0.z; av[3]=a0.w;
            av[4]=a1.x; av[5]=a1.y; av[6]=a1.z; av[7]=a1.w;
        }
        float4 bv0 = *(const float4*)(Wcat + (kt + b_k) * 2048 + bn + b_n);
        float4 bv1 = *(const float4*)(Wcat + (kt + b_k) * 2048 + bn + b_n + 4);
        #pragma unroll
        for (int q = 0; q < 8; ++q) As[a_k + q][a_m] = av[q];
        *(float4*)&Bs[b_k][b_n]     = bv0;
        *(float4*)&Bs[b_k][b_n + 4] = bv1;
        __syncthreads();
        #pragma unroll
        for (int kk = 0; kk < 16; ++kk) {
            float a[8], b[8];
            #pragma unroll
            for (int i = 0; i < 4; ++i) { a[i] = As[kk][ty*4 + i]; a[4+i] = As[kk][64 + ty*4 + i]; }
            #pragma unroll
            for (int j = 0; j < 4; ++j) { b[j] = Bs[kk][tx*4 + j]; b[4+j] = Bs[kk][64 + tx*4 + j]; }
            #pragma unroll
            for (int i = 0; i < 8; ++i)
                #pragma unroll
                for (int j = 0; j < 8; ++j)
                    acc[i][j] = fmaf(a[i], b[j], acc[i][j]);
        }
        __syncthreads();
    }

    #pragma unroll
    for (int ri = 0; ri < 2; ++ri) {
        #pragma unroll
        for (int i = 0; i < 4; ++i) {
            const int row = bm + ri*64 + ty*4 + i;
            const int b   = row >> 11;
            const int t   = row & (T_ - 1);
            #pragma unroll
            for (int rj = 0; rj < 2; ++rj) {
                #pragma unroll
                for (int j = 0; j < 4; ++j) {
                    const int col = bn + rj*64 + tx*4 + j;
                    const float val = acc[ri*4 + i][rj*4 + j];
                    if (col < 512) {
                        const int h = col >> 5, r = col & 31;
                        ql[((b*H_ + h)*T_ + t)*R_ + r] = val;
                    } else if (col < 1024) {
                        const int c = col - 512; const int h = c >> 5, r = c & 31;
                        kl[((b*H_ + h)*T_ + t)*R_ + r] = val;
                    } else {
                        const int c = col - 1024; const int h = c >> 6, dh = c & 63;
                        v[((b*H_ + h)*T_ + t)*DH_ + dh] = val;
                    }
                }
            }
        }
    }
}

// ---------------------------------------------------------------------------
// Kernel 2: register-resident flash attention (fp32 VALU).
// Block = (bh, q-tile of 64 rows), 256 threads as 16x16:
//   ti = tid>>4 (4-row group), tj = tid&15 (4-col group).
// Each thread: 4x4 scores/P in regs, 4x4 O accum, per-row m/l redundant
// across the 16-lane row group (shfl_xor reductions). P crosses to phase 3
// via one LDS round-trip. 3 barriers/tile. Heavy q-tiles dispatch first.
// ---------------------------------------------------------------------------
__global__ __launch_bounds__(256, 3) void attn_kernel(
    const float* __restrict__ ql, const float* __restrict__ kl,
    const float* __restrict__ v, float* __restrict__ y)
{
    __shared__ float qls[64][36];    // [t][r], stride 36 (144B, b128-aligned)
    __shared__ float klsT[32][68];   // [r][s], stride 68
    __shared__ float vs[64][64];     // [s][d]
    __shared__ float Ps[64][68];     // [t][s], stride 68

    const int tid = threadIdx.x;
    const int ti  = tid >> 4;            // 0..15: rows 4ti..4ti+3
    const int tj  = tid & 15;            // 0..15: cols 4tj..4tj+3
    const int qt  = 31 - (int)blockIdx.x; // heavy blocks first
    const int bh  = blockIdx.y;
    const int t0  = qt * 64;

    // stage qls[t][r] (64x32 contiguous floats in global)
    {
        const float4* src = (const float4*)(ql + (bh * T_ + t0) * R_);
        for (int e = tid; e < 512; e += 256) {
            float4 w = src[e];
            *(float4*)&qls[e >> 3][(e & 7) * 4] = w;
        }
    }

    float m[4], l[4], O[4][4];
    #pragma unroll
    for (int i = 0; i < 4; ++i) {
        m[i] = NEG_; l[i] = 0.f;
        #pragma unroll
        for (int j = 0; j < 4; ++j) O[i][j] = 0.f;
    }

    const int nt = qt + 1;
    for (int it = 0; it < nt; ++it) {
        const int s0 = it * 64;
        __syncthreads();   // prev iteration's readers of klsT/vs/Ps are done
        // stage klsT[r][s] (transpose of kl tile)
        {
            const float* src = kl + (bh * T_ + s0) * R_;
            for (int e = tid; e < 2048; e += 256)
                klsT[e & 31][e >> 5] = src[e];
        }
        // stage vs[s][d]
        {
            const float4* src = (const float4*)(v + (bh * T_ + s0) * DH_);
            for (int e = tid; e < 1024; e += 256) {
                float4 w = src[e];
                *(float4*)&vs[e >> 4][(e & 15) * 4] = w;
            }
        }
        __syncthreads();

        // phase 1: S[4][4] over r in chunks of 4 (b128 LDS reads only)
        float S[4][4];
        #pragma unroll
        for (int i = 0; i < 4; ++i)
            #pragma unroll
            for (int j = 0; j < 4; ++j) S[i][j] = 0.f;
        #pragma unroll
        for (int r = 0; r < R_; r += 4) {
            float4 qv[4], kv[4];
            #pragma unroll
            for (int i = 0; i < 4; ++i) qv[i] = *(const float4*)&qls[4*ti + i][r];
            #pragma unroll
            for (int c = 0; c < 4; ++c) kv[c] = *(const float4*)&klsT[r + c][4*tj];
            #pragma unroll
            for (int i = 0; i < 4; ++i) {
                const float* qa = (const float*)&qv[i];
                #pragma unroll
                for (int j = 0; j < 4; ++j) {
                    float s = S[i][j];
                    s = fmaf(qa[0], ((const float*)&kv[0])[j], s);
                    s = fmaf(qa[1], ((const float*)&kv[1])[j], s);
                    s = fmaf(qa[2], ((const float*)&kv[2])[j], s);
                    s = fmaf(qa[3], ((const float*)&kv[3])[j], s);
                    S[i][j] = s;
                }
            }
        }

        // causal mask: only the diagonal tile needs it
        if (it == nt - 1) {
            #pragma unroll
            for (int i = 0; i < 4; ++i)
                #pragma unroll
                for (int j = 0; j < 4; ++j)
                    if (4*tj + j > 4*ti + i) S[i][j] = NEG_;
        }

        // distributed online softmax (16-lane row groups)
        float rmax[4], rsum[4], P[4][4];
        #pragma unroll
        for (int i = 0; i < 4; ++i)
            rmax[i] = fmaxf(fmaxf(S[i][0], S[i][1]), fmaxf(S[i][2], S[i][3]));
        #pragma unroll
        for (int off = 1; off <= 8; off <<= 1)
            #pragma unroll
            for (int i = 0; i < 4; ++i)
                rmax[i] = fmaxf(rmax[i], __shfl_xor(rmax[i], off, 64));
        #pragma unroll
        for (int i = 0; i < 4; ++i) {
            const float mn = fmaxf(m[i], rmax[i]);
            const float alpha = __expf(m[i] - mn);
            m[i] = mn;
            float s0r = 0.f;
            #pragma unroll
            for (int j = 0; j < 4; ++j) {
                P[i][j] = __expf(S[i][j] - mn);
                s0r += P[i][j];
            }
            rsum[i] = s0r;
            l[i] *= alpha;
            #pragma unroll
            for (int j = 0; j < 4; ++j) O[i][j] *= alpha;
        }
        #pragma unroll
        for (int off = 1; off <= 8; off <<= 1)
            #pragma unroll
            for (int i = 0; i < 4; ++i)
                rsum[i] += __shfl_xor(rsum[i], off, 64);
        #pragma unroll
        for (int i = 0; i < 4; ++i) l[i] += rsum[i];

        // P -> LDS (b128 writes)
        #pragma unroll
        for (int i = 0; i < 4; ++i)
            *(float4*)&Ps[4*ti + i][4*tj] = *(float4*)&P[i][0];
        __syncthreads();

        // phase 3: O += P @ V over s in chunks of 4 (b128 LDS reads only)
        #pragma unroll 2
        for (int s = 0; s < 64; s += 4) {
            float4 pv[4], vv[4];
            #pragma unroll
            for (int i = 0; i < 4; ++i) pv[i] = *(const float4*)&Ps[4*ti + i][s];
            #pragma unroll
            for (int c = 0; c < 4; ++c) vv[c] = *(const float4*)&vs[s + c][4*tj];
            #pragma unroll
            for (int i = 0; i < 4; ++i) {
                const float* pa = (const float*)&pv[i];
                #pragma unroll
                for (int j = 0; j < 4; ++j) {
                    float o = O[i][j];
                    o = fmaf(pa[0], ((const float*)&vv[0])[j], o);
                    o = fmaf(pa[1], ((const float*)&vv[1])[j], o);
                    o = fmaf(pa[2], ((const float*)&vv[2])[j], o);
                    o = fmaf(pa[3], ((const float*)&vv[3])[j], o);
                    O[i][j] = o;
                }
            }
        }
    }

    // epilogue: divide by l, store float4
    const int b = bh >> 4, h = bh & 15;
    #pragma unroll
    for (int i = 0; i < 4; ++i) {
        const float rl = 1.0f / l[i];
        float4 o4;
        o4.x = O[i][0] * rl; o4.y = O[i][1] * rl;
        o4.z = O[i][2] * rl; o4.w = O[i][3] * rl;
        *(float4*)(y + (b * T_ + t0 + 4*ti + i) * D_ + h * DH_ + 4*tj) = o4;
    }
}

// ---------------------------------------------------------------------------
// Kernel 3: out = y_f32(4096,1024) @ Wo(1024,1024), fp32 store.
// 128x64 tile, 256 threads, 8x4 micro-tile, BK=16. Grid 16x32 = 512 blocks.
// ---------------------------------------------------------------------------
__global__ __launch_bounds__(256) void out_gemm(
    const float* __restrict__ y, const void* __restrict__ Wo,
    float* __restrict__ out, const int* __restrict__ flag)
{
    __shared__ float As[16][132];
    __shared__ float Bs[16][68];
    const int isbf = *flag;
    const int tid = threadIdx.x;
    const int bm  = blockIdx.y * 128;
    const int bn  = blockIdx.x * 64;
    const int a_m = tid >> 1;          // 0..127
    const int a_k = (tid & 1) * 8;     // 0 or 8
    const int b_k = tid >> 4;          // 0..15
    const int b_n = (tid & 15) * 4;    // 0..60
    const int tx  = tid & 15;          // col group (x4)
    const int ty  = tid >> 4;          // row group (x8)
    float acc[8][4];
    #pragma unroll
    for (int i = 0; i < 8; ++i)
        #pragma unroll
        for (int j = 0; j < 4; ++j) acc[i][j] = 0.f;

    for (int kt = 0; kt < D_; kt += 16) {
        float4 a0 = *(const float4*)(y + (bm + a_m) * D_ + kt + a_k);
        float4 a1 = *(const float4*)(y + (bm + a_m) * D_ + kt + a_k + 4);
        As[a_k+0][a_m] = a0.x; As[a_k+1][a_m] = a0.y;
        As[a_k+2][a_m] = a0.z; As[a_k+3][a_m] = a0.w;
        As[a_k+4][a_m] = a1.x; As[a_k+5][a_m] = a1.y;
        As[a_k+6][a_m] = a1.z; As[a_k+7][a_m] = a1.w;
        if (isbf) {
            uint2 bw = *(const uint2*)((const u16*)Wo + (kt + b_k) * D_ + bn + b_n);
            Bs[b_k][b_n+0] = bflo(bw.x); Bs[b_k][b_n+1] = bfhi(bw.x);
            Bs[b_k][b_n+2] = bflo(bw.y); Bs[b_k][b_n+3] = bfhi(bw.y);
        } else {
            float4 bv = *(const float4*)((const float*)Wo + (kt + b_k) * D_ + bn + b_n);
            *(float4*)&Bs[b_k][b_n] = bv;
        }
        __syncthreads();
        #pragma unroll
        for (int kk = 0; kk < 16; ++kk) {
            float a[8], b[4];
            #pragma unroll
            for (int i = 0; i < 8; ++i) a[i] = As[kk][ty*8 + i];
            #pragma unroll
            for (int j = 0; j < 4; ++j) b[j] = Bs[kk][tx*4 + j];
            #pragma unroll
            for (int i = 0; i < 8; ++i)
                #pragma unroll
                for (int j = 0; j < 4; ++j)
                    acc[i][j] = fmaf(a[i], b[j], acc[i][j]);
        }
        __syncthreads();
    }
    #pragma unroll
    for (int i = 0; i < 8; ++i) {
        float4 o4;
        o4.x = acc[i][0]; o4.y = acc[i][1]; o4.z = acc[i][2]; o4.w = acc[i][3];
        *(float4*)(out + (bm + ty*8 + i) * D_ + bn + tx*4) = o4;
    }
}

// ---------------------------------------------------------------------------
extern "C" void kernel_launch(void* const* d_in, const int* in_sizes, int n_in,
                              void* d_out, int out_size, void* d_ws, size_t ws_size,
                              hipStream_t stream)
{
    (void)out_size; (void)ws_size;
    const void* in_x = nullptr; const void* in_wqkv = nullptr;
    const void* in_wq = nullptr; const void* in_wk = nullptr;
    const void* in_core = nullptr; const void* in_wo = nullptr;
    for (int i = 0; i < n_in; ++i) {
        const int s = in_sizes[i];
        if      (s == BT_*D_)     { if (!in_x)    in_x    = d_in[i]; }
        else if (s == D_*3*D_)    { if (!in_wqkv) in_wqkv = d_in[i]; }
        else if (s == H_*DH_*R_)  { if (!in_wq)   in_wq   = d_in[i]; else if (!in_wk) in_wk = d_in[i]; }
        else if (s == H_*R_)      { if (!in_core) in_core = d_in[i]; }
        else if (s == D_*D_)      { if (!in_wo)   in_wo   = d_in[i]; }
    }
    if (!in_x)    in_x    = d_in[0];
    if (!in_wqkv) in_wqkv = d_in[1];
    if (!in_wq)   in_wq   = d_in[2];
    if (!in_wk)   in_wk   = d_in[3];
    if (!in_core) in_core = d_in[4];
    if (!in_wo)   in_wo   = d_in[5];

    float* out = (float*)d_out;

    float* ws   = (float*)d_ws;
    int*   flag = (int*)(ws + OFF_FLAG);
    float* Wcat = ws + OFF_WCAT;
    float* ql   = ws + OFF_QL;
    float* kl   = ws + OFF_KL;
    float* v    = ws + OFF_V;
    float* y    = ws + OFF_Y;

    detect_dtype<<<1, 64, 0, stream>>>((const u32*)in_x, flag);
    fold_weights<<<(D_*512)/256, 256, 0, stream>>>(in_wqkv, in_wq, in_wk, in_core, Wcat, flag);
    convert_wv<<<(D_*D_)/256, 256, 0, stream>>>(in_wqkv, Wcat, flag);
    fused_qkv_lsr_gemm<<<dim3(N1_/128, BT_/128), 256, 0, stream>>>(in_x, Wcat, ql, kl, v, flag);
    attn_kernel<<<dim3(T_/64, B_*H_), 256, 0, stream>>>(ql, kl, v, y);
    out_gemm<<<dim3(D_/64, BT_/128), 256, 0, stream>>>(y, in_wo, out, flag);
}

// Round 6
// 594.926 us; speedup vs baseline: 3.0362x; 1.8117x over previous
//
#include <hip/hip_runtime.h>
#include <hip/hip_bf16.h>

// Problem constants. Established rounds 0-5: inputs fp32 (detector = insurance),
// output fp32. Round-5 lesson: fp32 VALU attn is LDS-pipe + spill bound -> MFMA.
#define B_  2
#define T_  2048
#define D_  1024
#define H_  16
#define DH_ 64
#define R_  32
#define BT_ (B_*T_)          // 4096
#define N1_ 2048             // gemm1 cols: 512 ql + 512 kl + 1024 v
#define BH_ (B_*H_)          // 32

typedef unsigned short u16;
typedef unsigned int   u32;
typedef __attribute__((ext_vector_type(8))) short bhalf8;   // 8 bf16 = 4 VGPRs
typedef __attribute__((ext_vector_type(4))) float floatx4;  // MFMA C/D

// Workspace layout (bytes). Total ~50.3 MB.
#define WSB_FLAG 0
#define WSB_WCAT 256                          // fp32 1024x2048 = 8 MB
#define WSB_QL   (WSB_WCAT + 8388608)         // bf16 (B,H,T,R)  = 4 MB
#define WSB_KL   (WSB_QL   + 4194304)         // bf16 (B,H,T,R)  = 4 MB
#define WSB_V    (WSB_KL   + 4194304)         // bf16 (B,H,T,DH) = 8 MB
#define WSB_VT   (WSB_V    + 8388608)         // bf16 (B,H,DH,T) = 8 MB
#define WSB_Y    (WSB_VT   + 8388608)         // fp32 (B,T,D)    = 16 MB

#define NEG_ -1.0e30f

__device__ __forceinline__ float bfs(u16 s) {
    union { u32 i; float f; } w; w.i = ((u32)s) << 16; return w.f;
}
__device__ __forceinline__ float bflo(u32 u) {
    union { u32 i; float f; } w; w.i = u << 16; return w.f;
}
__device__ __forceinline__ float bfhi(u32 u) {
    union { u32 i; float f; } w; w.i = u & 0xFFFF0000u; return w.f;
}
__device__ __forceinline__ u16 tob(float f) {
    __hip_bfloat16 h = __float2bfloat16(f);   // RNE
    return *(u16*)&h;
}

// ---------------------------------------------------------------------------
// Kernel D: detect input dtype (1 = bf16, 0 = fp32) — insurance only.
// ---------------------------------------------------------------------------
__global__ __launch_bounds__(64) void detect_dtype(const u32* __restrict__ xw,
                                                   int* __restrict__ flag)
{
    const int tid = threadIdx.x;
    int hits = 0;
    for (int i = tid; i < 512; i += 64) {
        const u32 w = xw[i];
        const u32 h = w & 0xFFFFu;
        const u32 e = (h >> 7) & 0xFFu;
        if (h == 0u || (e >= 100u && e <= 150u)) ++hits;
    }
    #pragma unroll
    for (int off = 32; off; off >>= 1) hits += __shfl_down(hits, off, 64);
    if (tid == 0) *flag = (hits >= 300) ? 1 : 0;
}

// ---------------------------------------------------------------------------
// Kernel 0a: fold LSR weights (+ core + 1/sqrt(R)) into the QKV projection.
// ---------------------------------------------------------------------------
__global__ __launch_bounds__(256) void fold_weights(
    const void* __restrict__ Wqkv, const void* __restrict__ Wq_lsr,
    const void* __restrict__ Wk_lsr, const void* __restrict__ core,
    float* __restrict__ Wcat, const int* __restrict__ flag)
{
    const int isbf = *flag;
    const int idx = blockIdx.x * 256 + threadIdx.x;   // over D_*512
    const int d  = idx >> 9;
    const int hr = idx & 511;
    const int h  = hr >> 5;
    const int r  = hr & 31;
    float sq = 0.f, sk = 0.f, c;
    if (isbf) {
        const u16* W  = (const u16*)Wqkv;
        const u16* Aq = (const u16*)Wq_lsr;
        const u16* Ak = (const u16*)Wk_lsr;
        #pragma unroll
        for (int dh = 0; dh < DH_; ++dh) {
            const int wi = d * (3*D_) + h * DH_ + dh;
            const int ai = (h * DH_ + dh) * R_ + r;
            sq = fmaf(bfs(W[wi]),      bfs(Aq[ai]), sq);
            sk = fmaf(bfs(W[wi + D_]), bfs(Ak[ai]), sk);
        }
        c = bfs(((const u16*)core)[h * R_ + r]);
    } else {
        const float* W  = (const float*)Wqkv;
        const float* Aq = (const float*)Wq_lsr;
        const float* Ak = (const float*)Wk_lsr;
        #pragma unroll
        for (int dh = 0; dh < DH_; ++dh) {
            const int wi = d * (3*D_) + h * DH_ + dh;
            const int ai = (h * DH_ + dh) * R_ + r;
            sq = fmaf(W[wi],      Aq[ai], sq);
            sk = fmaf(W[wi + D_], Ak[ai], sk);
        }
        c = ((const float*)core)[h * R_ + r];
    }
    const float scale = 0.17677669529663687f;  // 1/sqrt(32)
    Wcat[d * 2048 + hr]       = sq * c * scale;
    Wcat[d * 2048 + 512 + hr] = sk;
}

// Kernel 0b: copy V slice of Wqkv into Wcat cols 1024..2047 (fp32)
__global__ __launch_bounds__(256) void convert_wv(
    const void* __restrict__ Wqkv, float* __restrict__ Wcat,
    const int* __restrict__ flag)
{
    const int isbf = *flag;
    const int idx = blockIdx.x * 256 + threadIdx.x;   // over D_*D_
    const int d = idx >> 10;
    const int c = idx & 1023;
    const int src = d * (3*D_) + 2*D_ + c;
    Wcat[d * 2048 + 1024 + c] =
        isbf ? bfs(((const u16*)Wqkv)[src]) : ((const float*)Wqkv)[src];
}

// ---------------------------------------------------------------------------
// Kernel 1: gemm1  x(4096,1024) @ Wcat_f32(1024,2048), fp32 accum.
// 128x128 tile, 256 threads, 8x8 micro-tile, BK=16. Epilogue stores BF16
// scattered into ql/kl (B,H,T,R) and v (B,H,T,DH).
// ---------------------------------------------------------------------------
__global__ __launch_bounds__(256) void fused_qkv_lsr_gemm(
    const void* __restrict__ x, const float* __restrict__ Wcat,
    u16* __restrict__ ql, u16* __restrict__ kl, u16* __restrict__ v,
    const int* __restrict__ flag)
{
    __shared__ float As[16][132];
    __shared__ float Bs[16][132];
    const int isbf = *flag;
    const int tid = threadIdx.x;
    const int bm  = blockIdx.y * 128;
    const int bn  = blockIdx.x * 128;

    const int a_m = tid >> 1;
    const int a_k = (tid & 1) * 8;
    const int b_k = tid >> 4;
    const int b_n = (tid & 15) * 8;
    const int tx  = tid & 15;
    const int ty  = tid >> 4;

    float acc[8][8];
    #pragma unroll
    for (int i = 0; i < 8; ++i)
        #pragma unroll
        for (int j = 0; j < 8; ++j) acc[i][j] = 0.f;

    for (int kt = 0; kt < D_; kt += 16) {
        float av[8];
        if (isbf) {
            uint4 xv = *(const uint4*)((const u16*)x + (bm + a_m) * D_ + kt + a_k);
            av[0]=bflo(xv.x); av[1]=bfhi(xv.x); av[2]=bflo(xv.y); av[3]=bfhi(xv.y);
            av[4]=bflo(xv.z); av[5]=bfhi(xv.z); av[6]=bflo(xv.w); av[7]=bfhi(xv.w);
        } else {
            float4 a0 = *(const float4*)((const float*)x + (bm + a_m) * D_ + kt + a_k);
            float4 a1 = *(const float4*)((const float*)x + (bm + a_m) * D_ + kt + a_k + 4);
            av[0]=a0.x; av[1]=a0.y; av[2]=a0.z; av[3]=a0.w;
            av[4]=a1.x; av[5]=a1.y; av[6]=a1.z; av[7]=a1.w;
        }
        float4 bv0 = *(const float4*)(Wcat + (kt + b_k) * 2048 + bn + b_n);
        float4 bv1 = *(const float4*)(Wcat + (kt + b_k) * 2048 + bn + b_n + 4);
        #pragma unroll
        for (int q = 0; q < 8; ++q) As[a_k + q][a_m] = av[q];
        *(float4*)&Bs[b_k][b_n]     = bv0;
        *(float4*)&Bs[b_k][b_n + 4] = bv1;
        __syncthreads();
        #pragma unroll
        for (int kk = 0; kk < 16; ++kk) {
            float a[8], b[8];
            #pragma unroll
            for (int i = 0; i < 4; ++i) { a[i] = As[kk][ty*4 + i]; a[4+i] = As[kk][64 + ty*4 + i]; }
            #pragma unroll
            for (int j = 0; j < 4; ++j) { b[j] = Bs[kk][tx*4 + j]; b[4+j] = Bs[kk][64 + tx*4 + j]; }
            #pragma unroll
            for (int i = 0; i < 8; ++i)
                #pragma unroll
                for (int j = 0; j < 8; ++j)
                    acc[i][j] = fmaf(a[i], b[j], acc[i][j]);
        }
        __syncthreads();
    }

    #pragma unroll
    for (int ri = 0; ri < 2; ++ri) {
        #pragma unroll
        for (int i = 0; i < 4; ++i) {
            const int row = bm + ri*64 + ty*4 + i;
            const int b   = row >> 11;
            const int t   = row & (T_ - 1);
            #pragma unroll
            for (int rj = 0; rj < 2; ++rj) {
                #pragma unroll
                for (int j = 0; j < 4; ++j) {
                    const int col = bn + rj*64 + tx*4 + j;
                    const u16 val = tob(acc[ri*4 + i][rj*4 + j]);
                    if (col < 512) {
                        const int h = col >> 5, r = col & 31;
                        ql[((b*H_ + h)*T_ + t)*R_ + r] = val;
                    } else if (col < 1024) {
                        const int c = col - 512; const int h = c >> 5, r = c & 31;
                        kl[((b*H_ + h)*T_ + t)*R_ + r] = val;
                    } else {
                        const int c = col - 1024; const int h = c >> 6, dh = c & 63;
                        v[((b*H_ + h)*T_ + t)*DH_ + dh] = val;
                    }
                }
            }
        }
    }
}

// ---------------------------------------------------------------------------
// Kernel 1b: transpose v (B,H,T,DH) -> v_t (B,H,DH,T), bf16, 64x64 LDS tiles.
// ---------------------------------------------------------------------------
__global__ __launch_bounds__(256) void transpose_v(
    const u16* __restrict__ v, u16* __restrict__ v_t)
{
    __shared__ u16 tile[64 * 72];
    const int tid = threadIdx.x;
    const int st  = blockIdx.x;   // 0..31 (t tile)
    const int bh  = blockIdx.y;   // 0..31
    #pragma unroll
    for (int p = 0; p < 2; ++p) {
        const int e = tid + p * 256;          // 0..511
        const int r = e >> 3, ch = e & 7;
        uint4 w = *(const uint4*)(v + ((size_t)bh * T_ + st*64 + r) * DH_ + ch*8);
        *(uint4*)&tile[r * 72 + ch*8] = w;
    }
    __syncthreads();
    #pragma unroll
    for (int p = 0; p < 2; ++p) {
        const int e = tid + p * 256;
        const int d = e >> 3, ch = e & 7;
        u16 tmp[8];
        #pragma unroll
        for (int j = 0; j < 8; ++j) tmp[j] = tile[(ch*8 + j) * 72 + d];
        *(uint4*)(v_t + ((size_t)(bh * DH_ + d)) * T_ + st*64 + ch*8) = *(uint4*)tmp;
    }
}

// ---------------------------------------------------------------------------
// Kernel 2: MFMA flash attention (bf16 inputs, fp32 softmax/accum).
// Block = (bh, 64-row q-tile), 256 threads = 4 waves; wave w owns q-rows
// w*16..w*16+15. Per s-tile: S-strip = 4x mfma_f32_16x16x32_bf16 (R=32 in one
// pass), distributed online softmax in C-layout (16-lane shfl_xor), P->LDS
// (wave-private strip, no barrier), PV = 8 MFMA. O stays in C-layout regs.
// Layouts (m89/m91-verified): C/D col=lane&15,row=quad*4+reg;
// A[m=lane&15][k=quad*8+j]; B[k=quad*8+j][n=lane&15].
// ---------------------------------------------------------------------------
__global__ __launch_bounds__(256) void attn_kernel(
    const u16* __restrict__ ql, const u16* __restrict__ kl,
    const u16* __restrict__ v_t, float* __restrict__ y)
{
    __shared__ u16 qls[64 * 40];   // [t][r], stride 40 (80B, 16B-aligned)
    __shared__ u16 kls[64 * 40];   // [s][r]
    __shared__ u16 vsT[64 * 72];   // [d][s], stride 72 (144B)
    __shared__ u16 Ps [64 * 72];   // [t][s]

    const int tid  = threadIdx.x;
    const int lane = tid & 63;
    const int w    = tid >> 6;          // wave 0..3
    const int n16  = lane & 15;
    const int q4   = lane >> 4;         // quad 0..3
    const int qt   = 31 - (int)blockIdx.x;  // heavy q-tiles first
    const int bh   = blockIdx.y;
    const int t0   = qt * 64;

    // stage qls (wave-private rows: tid>>2 = w*16 + ...)
    {
        const int e = tid;              // 256 uint4 = 64 rows x 4 chunks
        const int r = e >> 2, ch = e & 3;
        uint4 x = *(const uint4*)(ql + ((size_t)bh * T_ + t0 + r) * R_ + ch*8);
        *(uint4*)&qls[r * 40 + ch*8] = x;
    }
    // resident A-fragment: q rows w*16 + n16, k = q4*8..+7
    bhalf8 aq = *(const bhalf8*)&qls[(w*16 + n16) * 40 + q4*8];

    float m[4], l[4];
    floatx4 O[4];
    #pragma unroll
    for (int r = 0; r < 4; ++r) { m[r] = NEG_; l[r] = 0.f; }
    #pragma unroll
    for (int c = 0; c < 4; ++c) O[c] = (floatx4)(0.f);

    const int nt = qt + 1;
    for (int it = 0; it < nt; ++it) {
        const int s0 = it * 64;
        __syncthreads();   // prev tile's readers of kls/vsT done
        // stage kls: 256 uint4
        {
            const int e = tid;
            const int r = e >> 2, ch = e & 3;
            uint4 x = *(const uint4*)(kl + ((size_t)bh * T_ + s0 + r) * R_ + ch*8);
            *(uint4*)&kls[r * 40 + ch*8] = x;
        }
        // stage vsT from v_t (already transposed): 512 uint4
        #pragma unroll
        for (int p = 0; p < 2; ++p) {
            const int e = tid + p * 256;
            const int d = e >> 3, ch = e & 7;
            uint4 x = *(const uint4*)(v_t + ((size_t)(bh * DH_ + d)) * T_ + s0 + ch*8);
            *(uint4*)&vsT[d * 72 + ch*8] = x;
        }
        __syncthreads();

        // QK: 4 subtiles (cols 16c..16c+15)
        floatx4 Sc[4];
        #pragma unroll
        for (int c = 0; c < 4; ++c) {
            bhalf8 bk = *(const bhalf8*)&kls[(16*c + n16) * 40 + q4*8];
            Sc[c] = __builtin_amdgcn_mfma_f32_16x16x32_bf16(aq, bk, (floatx4)(0.f), 0, 0, 0);
        }

        // causal mask (diagonal tile only): s = 16c+n16, t = w*16 + q4*4 + r
        if (it == nt - 1) {
            const int trow = w*16 + q4*4;
            #pragma unroll
            for (int c = 0; c < 4; ++c) {
                const int s = 16*c + n16;
                #pragma unroll
                for (int r = 0; r < 4; ++r)
                    if (s > trow + r) Sc[c][r] = NEG_;
            }
        }

        // distributed online softmax (rows = quad*4 + r; reduce over 16 lanes)
        float rmax[4];
        #pragma unroll
        for (int r = 0; r < 4; ++r)
            rmax[r] = fmaxf(fmaxf(Sc[0][r], Sc[1][r]), fmaxf(Sc[2][r], Sc[3][r]));
        #pragma unroll
        for (int off = 1; off <= 8; off <<= 1)
            #pragma unroll
            for (int r = 0; r < 4; ++r)
                rmax[r] = fmaxf(rmax[r], __shfl_xor(rmax[r], off, 64));

        float alpha[4], rsum[4];
        float P[4][4];
        #pragma unroll
        for (int r = 0; r < 4; ++r) {
            const float mn = fmaxf(m[r], rmax[r]);
            alpha[r] = __expf(m[r] - mn);
            m[r] = mn;
            float s = 0.f;
            #pragma unroll
            for (int c = 0; c < 4; ++c) {
                P[c][r] = __expf(Sc[c][r] - mn);
                s += P[c][r];
            }
            rsum[r] = s;
        }
        #pragma unroll
        for (int off = 1; off <= 8; off <<= 1)
            #pragma unroll
            for (int r = 0; r < 4; ++r)
                rsum[r] += __shfl_xor(rsum[r], off, 64);
        #pragma unroll
        for (int r = 0; r < 4; ++r) l[r] = l[r] * alpha[r] + rsum[r];
        #pragma unroll
        for (int c = 0; c < 4; ++c)
            #pragma unroll
            for (int r = 0; r < 4; ++r)
                O[c][r] *= alpha[r];

        // P -> LDS bf16 (wave-private strip; in-wave dep, compiler waits)
        #pragma unroll
        for (int c = 0; c < 4; ++c)
            #pragma unroll
            for (int r = 0; r < 4; ++r)
                Ps[(w*16 + q4*4 + r) * 72 + 16*c + n16] = tob(P[c][r]);

        // PV: O[c] += P(16x64) @ V(64x16-col-block c), K split in 2x32
        bhalf8 pa0 = *(const bhalf8*)&Ps[(w*16 + n16) * 72 +  0 + q4*8];
        bhalf8 pa1 = *(const bhalf8*)&Ps[(w*16 + n16) * 72 + 32 + q4*8];
        #pragma unroll
        for (int c = 0; c < 4; ++c) {
            bhalf8 bv0 = *(const bhalf8*)&vsT[(16*c + n16) * 72 +  0 + q4*8];
            bhalf8 bv1 = *(const bhalf8*)&vsT[(16*c + n16) * 72 + 32 + q4*8];
            O[c] = __builtin_amdgcn_mfma_f32_16x16x32_bf16(pa0, bv0, O[c], 0, 0, 0);
            O[c] = __builtin_amdgcn_mfma_f32_16x16x32_bf16(pa1, bv1, O[c], 0, 0, 0);
        }
    }

    // epilogue: O / l -> y (C-layout scatter; 16-lane-contiguous 64B segments)
    const int b = bh >> 4, h = bh & 15;
    #pragma unroll
    for (int r = 0; r < 4; ++r) {
        const float rl = 1.0f / l[r];
        const int t = t0 + w*16 + q4*4 + r;
        #pragma unroll
        for (int c = 0; c < 4; ++c)
            y[((size_t)b * T_ + t) * D_ + h * DH_ + 16*c + n16] = O[c][r] * rl;
    }
}

// ---------------------------------------------------------------------------
// Kernel 3: out = y_f32(4096,1024) @ Wo(1024,1024), fp32 store.
// 128x64 tile, 256 threads, 8x4 micro-tile, BK=16.
// ---------------------------------------------------------------------------
__global__ __launch_bounds__(256) void out_gemm(
    const float* __restrict__ y, const void* __restrict__ Wo,
    float* __restrict__ out, const int* __restrict__ flag)
{
    __shared__ float As[16][132];
    __shared__ float Bs[16][68];
    const int isbf = *flag;
    const int tid = threadIdx.x;
    const int bm  = blockIdx.y * 128;
    const int bn  = blockIdx.x * 64;
    const int a_m = tid >> 1;
    const int a_k = (tid & 1) * 8;
    const int b_k = tid >> 4;
    const int b_n = (tid & 15) * 4;
    const int tx  = tid & 15;
    const int ty  = tid >> 4;
    float acc[8][4];
    #pragma unroll
    for (int i = 0; i < 8; ++i)
        #pragma unroll
        for (int j = 0; j < 4; ++j) acc[i][j] = 0.f;

    for (int kt = 0; kt < D_; kt += 16) {
        float4 a0 = *(const float4*)(y + (bm + a_m) * D_ + kt + a_k);
        float4 a1 = *(const float4*)(y + (bm + a_m) * D_ + kt + a_k + 4);
        As[a_k+0][a_m] = a0.x; As[a_k+1][a_m] = a0.y;
        As[a_k+2][a_m] = a0.z; As[a_k+3][a_m] = a0.w;
        As[a_k+4][a_m] = a1.x; As[a_k+5][a_m] = a1.y;
        As[a_k+6][a_m] = a1.z; As[a_k+7][a_m] = a1.w;
        if (isbf) {
            uint2 bw = *(const uint2*)((const u16*)Wo + (kt + b_k) * D_ + bn + b_n);
            Bs[b_k][b_n+0] = bflo(bw.x); Bs[b_k][b_n+1] = bfhi(bw.x);
            Bs[b_k][b_n+2] = bflo(bw.y); Bs[b_k][b_n+3] = bfhi(bw.y);
        } else {
            float4 bv = *(const float4*)((const float*)Wo + (kt + b_k) * D_ + bn + b_n);
            *(float4*)&Bs[b_k][b_n] = bv;
        }
        __syncthreads();
        #pragma unroll
        for (int kk = 0; kk < 16; ++kk) {
            float a[8], b[4];
            #pragma unroll
            for (int i = 0; i < 8; ++i) a[i] = As[kk][ty*8 + i];
            #pragma unroll
            for (int j = 0; j < 4; ++j) b[j] = Bs[kk][tx*4 + j];
            #pragma unroll
            for (int i = 0; i < 8; ++i)
                #pragma unroll
                for (int j = 0; j < 4; ++j)
                    acc[i][j] = fmaf(a[i], b[j], acc[i][j]);
        }
        __syncthreads();
    }
    #pragma unroll
    for (int i = 0; i < 8; ++i) {
        float4 o4;
        o4.x = acc[i][0]; o4.y = acc[i][1]; o4.z = acc[i][2]; o4.w = acc[i][3];
        *(float4*)(out + (bm + ty*8 + i) * D_ + bn + tx*4) = o4;
    }
}

// ---------------------------------------------------------------------------
extern "C" void kernel_launch(void* const* d_in, const int* in_sizes, int n_in,
                              void* d_out, int out_size, void* d_ws, size_t ws_size,
                              hipStream_t stream)
{
    (void)out_size; (void)ws_size;
    const void* in_x = nullptr; const void* in_wqkv = nullptr;
    const void* in_wq = nullptr; const void* in_wk = nullptr;
    const void* in_core = nullptr; const void* in_wo = nullptr;
    for (int i = 0; i < n_in; ++i) {
        const int s = in_sizes[i];
        if      (s == BT_*D_)     { if (!in_x)    in_x    = d_in[i]; }
        else if (s == D_*3*D_)    { if (!in_wqkv) in_wqkv = d_in[i]; }
        else if (s == H_*DH_*R_)  { if (!in_wq)   in_wq   = d_in[i]; else if (!in_wk) in_wk = d_in[i]; }
        else if (s == H_*R_)      { if (!in_core) in_core = d_in[i]; }
        else if (s == D_*D_)      { if (!in_wo)   in_wo   = d_in[i]; }
    }
    if (!in_x)    in_x    = d_in[0];
    if (!in_wqkv) in_wqkv = d_in[1];
    if (!in_wq)   in_wq   = d_in[2];
    if (!in_wk)   in_wk   = d_in[3];
    if (!in_core) in_core = d_in[4];
    if (!in_wo)   in_wo   = d_in[5];

    float* out = (float*)d_out;

    char* ws   = (char*)d_ws;
    int*  flag = (int*)(ws + WSB_FLAG);
    float* Wcat = (float*)(ws + WSB_WCAT);
    u16*  ql   = (u16*)(ws + WSB_QL);
    u16*  kl   = (u16*)(ws + WSB_KL);
    u16*  v    = (u16*)(ws + WSB_V);
    u16*  v_t  = (u16*)(ws + WSB_VT);
    float* y   = (float*)(ws + WSB_Y);

    detect_dtype<<<1, 64, 0, stream>>>((const u32*)in_x, flag);
    fold_weights<<<(D_*512)/256, 256, 0, stream>>>(in_wqkv, in_wq, in_wk, in_core, Wcat, flag);
    convert_wv<<<(D_*D_)/256, 256, 0, stream>>>(in_wqkv, Wcat, flag);
    fused_qkv_lsr_gemm<<<dim3(N1_/128, BT_/128), 256, 0, stream>>>(in_x, Wcat, ql, kl, v, flag);
    transpose_v<<<dim3(T_/64, BH_), 256, 0, stream>>>(v, v_t);
    attn_kernel<<<dim3(T_/64, BH_), 256, 0, stream>>>(ql, kl, v_t, y);
    out_gemm<<<dim3(D_/64, BT_/128), 256, 0, stream>>>(y, in_wo, out, flag);
}

// Round 7
// 288.987 us; speedup vs baseline: 6.2505x; 2.0587x over previous
//
#include <hip/hip_runtime.h>
#include <hip/hip_bf16.h>

// Problem constants. Established rounds 0-6: inputs fp32 (detector=insurance),
// output fp32. R5: fp32 VALU attn LDS/spill-bound -> MFMA (r6: 700->~120us).
// R6: both fp32 GEMMs VALU-bound (157 TF ceiling) -> bf16 MFMA this round.
#define B_  2
#define T_  2048
#define D_  1024
#define H_  16
#define DH_ 64
#define R_  32
#define BT_ (B_*T_)          // 4096
#define BH_ (B_*H_)          // 32

typedef unsigned short u16;
typedef unsigned int   u32;
typedef __attribute__((ext_vector_type(8))) short bhalf8;   // 8 bf16 = 4 VGPRs
typedef __attribute__((ext_vector_type(4))) float floatx4;  // MFMA C/D

// Workspace layout (bytes). Total ~52.4 MB.
#define WSB_FLAG  0
#define WSB_XB    256                        // bf16 x       (4096,1024)  8 MB
#define WSB_WCAT  (WSB_XB   + 8388608)       // bf16 Wcat    (1024,2048)  4 MB
#define WSB_WCATT (WSB_WCAT + 4194304)       // bf16 WcatT   (2048,1024)  4 MB
#define WSB_QL    (WSB_WCATT+ 4194304)       // bf16 (B,H,T,R)            4 MB
#define WSB_KL    (WSB_QL   + 4194304)       // bf16 (B,H,T,R)            4 MB
#define WSB_V     (WSB_KL   + 4194304)       // bf16 (B,H,T,DH)           8 MB
#define WSB_VT    (WSB_V    + 8388608)       // bf16 (B,H,DH,T)           8 MB
#define WSB_YB    (WSB_VT   + 8388608)       // bf16 y       (B,T,D)      8 MB
#define WSB_WOT   (WSB_YB   + 8388608)       // bf16 WoT     (1024,1024)  2 MB

#define NEG_ -1.0e30f

__device__ __forceinline__ float bfs(u16 s) {
    union { u32 i; float f; } w; w.i = ((u32)s) << 16; return w.f;
}
__device__ __forceinline__ u16 tob(float f) {
    __hip_bfloat16 h = __float2bfloat16(f);   // RNE
    return *(u16*)&h;
}

// ---------------------------------------------------------------------------
// Kernel D: detect input dtype (1 = bf16, 0 = fp32) — insurance only.
// ---------------------------------------------------------------------------
__global__ __launch_bounds__(64) void detect_dtype(const u32* __restrict__ xw,
                                                   int* __restrict__ flag)
{
    const int tid = threadIdx.x;
    int hits = 0;
    for (int i = tid; i < 512; i += 64) {
        const u32 w = xw[i];
        const u32 h = w & 0xFFFFu;
        const u32 e = (h >> 7) & 0xFFu;
        if (h == 0u || (e >= 100u && e <= 150u)) ++hits;
    }
    #pragma unroll
    for (int off = 32; off; off >>= 1) hits += __shfl_down(hits, off, 64);
    if (tid == 0) *flag = (hits >= 300) ? 1 : 0;
}

// ---------------------------------------------------------------------------
// Kernel C: x -> xb bf16 (8 elems/thread).
// ---------------------------------------------------------------------------
__global__ __launch_bounds__(256) void convert_x(
    const void* __restrict__ x, u16* __restrict__ xb,
    const int* __restrict__ flag)
{
    const int isbf = *flag;
    const int e = blockIdx.x * 256 + threadIdx.x;  // over 524288 (x8 elems)
    if (isbf) {
        ((uint4*)xb)[e] = ((const uint4*)x)[e];
    } else {
        float4 a0 = ((const float4*)x)[2*e];
        float4 a1 = ((const float4*)x)[2*e + 1];
        u16 t[8] = { tob(a0.x), tob(a0.y), tob(a0.z), tob(a0.w),
                     tob(a1.x), tob(a1.y), tob(a1.z), tob(a1.w) };
        *(uint4*)(xb + (size_t)e * 8) = *(uint4*)t;
    }
}

// ---------------------------------------------------------------------------
// Kernel 0a: fold LSR weights (+ core + 1/sqrt(R)) -> Wcat cols 0..1023 (bf16)
// ---------------------------------------------------------------------------
__global__ __launch_bounds__(256) void fold_weights(
    const void* __restrict__ Wqkv, const void* __restrict__ Wq_lsr,
    const void* __restrict__ Wk_lsr, const void* __restrict__ core,
    u16* __restrict__ Wcat, const int* __restrict__ flag)
{
    const int isbf = *flag;
    const int idx = blockIdx.x * 256 + threadIdx.x;   // over D_*512
    const int d  = idx >> 9;
    const int hr = idx & 511;
    const int h  = hr >> 5;
    const int r  = hr & 31;
    float sq = 0.f, sk = 0.f, c;
    if (isbf) {
        const u16* W  = (const u16*)Wqkv;
        const u16* Aq = (const u16*)Wq_lsr;
        const u16* Ak = (const u16*)Wk_lsr;
        #pragma unroll
        for (int dh = 0; dh < DH_; ++dh) {
            const int wi = d * (3*D_) + h * DH_ + dh;
            const int ai = (h * DH_ + dh) * R_ + r;
            sq = fmaf(bfs(W[wi]),      bfs(Aq[ai]), sq);
            sk = fmaf(bfs(W[wi + D_]), bfs(Ak[ai]), sk);
        }
        c = bfs(((const u16*)core)[h * R_ + r]);
    } else {
        const float* W  = (const float*)Wqkv;
        const float* Aq = (const float*)Wq_lsr;
        const float* Ak = (const float*)Wk_lsr;
        #pragma unroll
        for (int dh = 0; dh < DH_; ++dh) {
            const int wi = d * (3*D_) + h * DH_ + dh;
            const int ai = (h * DH_ + dh) * R_ + r;
            sq = fmaf(W[wi],      Aq[ai], sq);
            sk = fmaf(W[wi + D_], Ak[ai], sk);
        }
        c = ((const float*)core)[h * R_ + r];
    }
    const float scale = 0.17677669529663687f;  // 1/sqrt(32)
    Wcat[d * 2048 + hr]       = tob(sq * c * scale);
    Wcat[d * 2048 + 512 + hr] = tob(sk);
}

// Kernel 0b: V slice of Wqkv -> Wcat cols 1024..2047 (bf16)
__global__ __launch_bounds__(256) void convert_wv(
    const void* __restrict__ Wqkv, u16* __restrict__ Wcat,
    const int* __restrict__ flag)
{
    const int isbf = *flag;
    const int idx = blockIdx.x * 256 + threadIdx.x;   // over D_*D_
    const int d = idx >> 10;
    const int c = idx & 1023;
    const int src = d * (3*D_) + 2*D_ + c;
    const float vv = isbf ? bfs(((const u16*)Wqkv)[src]) : ((const float*)Wqkv)[src];
    Wcat[d * 2048 + 1024 + c] = tob(vv);
}

// ---------------------------------------------------------------------------
// Kernel T: bf16 tile transpose  dst[c][r] = src[r][c], 64x64 tiles.
// ---------------------------------------------------------------------------
__global__ __launch_bounds__(256) void transpose_b16(
    const u16* __restrict__ src, u16* __restrict__ dst,
    int srows, int scols)
{
    __shared__ __align__(16) u16 tile[64 * 72];
    const int tid = threadIdx.x;
    const int j0  = blockIdx.x * 64;   // src col
    const int i0  = blockIdx.y * 64;   // src row
    #pragma unroll
    for (int p = 0; p < 2; ++p) {
        const int e = tid + p * 256;
        const int r = e >> 3, ch = e & 7;
        uint4 w = *(const uint4*)(src + (size_t)(i0 + r) * scols + j0 + ch*8);
        *(uint4*)&tile[r * 72 + ch*8] = w;
    }
    __syncthreads();
    #pragma unroll
    for (int p = 0; p < 2; ++p) {
        const int e = tid + p * 256;
        const int c = e >> 3, ch = e & 7;
        u16 tmp[8];
        #pragma unroll
        for (int j = 0; j < 8; ++j) tmp[j] = tile[(ch*8 + j) * 72 + c];
        *(uint4*)(dst + (size_t)(j0 + c) * srows + i0 + ch*8) = *(uint4*)tmp;
    }
}

// Kernel T2: Wo (fp32/bf16) -> WoT bf16 transposed (1024x1024).
__global__ __launch_bounds__(256) void convert_woT(
    const void* __restrict__ Wo, u16* __restrict__ WoT,
    const int* __restrict__ flag)
{
    __shared__ __align__(16) u16 tile[64 * 72];
    const int isbf = *flag;
    const int tid = threadIdx.x;
    const int j0  = blockIdx.x * 64;   // n
    const int i0  = blockIdx.y * 64;   // k
    #pragma unroll
    for (int p = 0; p < 2; ++p) {
        const int e = tid + p * 256;
        const int r = e >> 3, ch = e & 7;
        if (isbf) {
            uint4 w = *(const uint4*)((const u16*)Wo + (size_t)(i0 + r) * D_ + j0 + ch*8);
            *(uint4*)&tile[r * 72 + ch*8] = w;
        } else {
            const float* s = (const float*)Wo + (size_t)(i0 + r) * D_ + j0 + ch*8;
            float4 a0 = *(const float4*)s;
            float4 a1 = *(const float4*)(s + 4);
            u16 t[8] = { tob(a0.x), tob(a0.y), tob(a0.z), tob(a0.w),
                         tob(a1.x), tob(a1.y), tob(a1.z), tob(a1.w) };
            *(uint4*)&tile[r * 72 + ch*8] = *(uint4*)t;
        }
    }
    __syncthreads();
    #pragma unroll
    for (int p = 0; p < 2; ++p) {
        const int e = tid + p * 256;
        const int c = e >> 3, ch = e & 7;
        u16 tmp[8];
        #pragma unroll
        for (int j = 0; j < 8; ++j) tmp[j] = tile[(ch*8 + j) * 72 + c];
        *(uint4*)(WoT + (size_t)(j0 + c) * D_ + i0 + ch*8) = *(uint4*)tmp;
    }
}

// ---------------------------------------------------------------------------
// Kernel 1: MFMA gemm1  xb(4096,1024) @ WcatT^T -> scatter ql/kl/v (bf16).
// 128x128 tile, BK=64, 4 waves 2x2, each wave 64x64 (16 MFMA accs).
// A-frag: As[m][k-contig]; B-frag: Bs[n][k-contig]; both b128 LDS reads.
// ---------------------------------------------------------------------------
__global__ __launch_bounds__(256) void gemm1_mfma(
    const u16* __restrict__ xb, const u16* __restrict__ WcatT,
    u16* __restrict__ ql, u16* __restrict__ kl, u16* __restrict__ v)
{
    __shared__ __align__(16) u16 As[128 * 72];
    __shared__ __align__(16) u16 Bs[128 * 72];
    const int tid  = threadIdx.x;
    const int lane = tid & 63;
    const int w    = tid >> 6;
    const int n16  = lane & 15;
    const int q4   = lane >> 4;
    const int wx   = w & 1;          // n-half
    const int wy   = w >> 1;         // m-half
    const int bm   = blockIdx.y * 128;
    const int bn   = blockIdx.x * 128;

    floatx4 acc[4][4];
    #pragma unroll
    for (int i = 0; i < 4; ++i)
        #pragma unroll
        for (int j = 0; j < 4; ++j) acc[i][j] = (floatx4)(0.f);

    for (int kt = 0; kt < D_; kt += 64) {
        #pragma unroll
        for (int p = 0; p < 4; ++p) {
            const int e = tid + p * 256;       // 0..1023
            const int r = e >> 3, ch = e & 7;
            uint4 wa = *(const uint4*)(xb    + (size_t)(bm + r) * D_ + kt + ch*8);
            uint4 wb = *(const uint4*)(WcatT + (size_t)(bn + r) * D_ + kt + ch*8);
            *(uint4*)&As[r * 72 + ch*8] = wa;
            *(uint4*)&Bs[r * 72 + ch*8] = wb;
        }
        __syncthreads();
        #pragma unroll
        for (int kk = 0; kk < 2; ++kk) {
            bhalf8 a[4], b[4];
            #pragma unroll
            for (int mi = 0; mi < 4; ++mi)
                a[mi] = *(const bhalf8*)&As[(wy*64 + mi*16 + n16) * 72 + kk*32 + q4*8];
            #pragma unroll
            for (int ni = 0; ni < 4; ++ni)
                b[ni] = *(const bhalf8*)&Bs[(wx*64 + ni*16 + n16) * 72 + kk*32 + q4*8];
            #pragma unroll
            for (int mi = 0; mi < 4; ++mi)
                #pragma unroll
                for (int ni = 0; ni < 4; ++ni)
                    acc[mi][ni] = __builtin_amdgcn_mfma_f32_16x16x32_bf16(
                        a[mi], b[ni], acc[mi][ni], 0, 0, 0);
        }
        __syncthreads();
    }

    // epilogue: C-layout (row = q4*4+rr, col = n16) scatter to ql/kl/v
    #pragma unroll
    for (int mi = 0; mi < 4; ++mi) {
        #pragma unroll
        for (int rr = 0; rr < 4; ++rr) {
            const int row = bm + wy*64 + mi*16 + q4*4 + rr;
            const int b   = row >> 11;
            const int t   = row & (T_ - 1);
            #pragma unroll
            for (int ni = 0; ni < 4; ++ni) {
                const int col = bn + wx*64 + ni*16 + n16;
                const u16 val = tob(acc[mi][ni][rr]);
                if (col < 512) {
                    const int h = col >> 5, r = col & 31;
                    ql[((size_t)(b*H_ + h)*T_ + t)*R_ + r] = val;
                } else if (col < 1024) {
                    const int c = col - 512; const int h = c >> 5, r = c & 31;
                    kl[((size_t)(b*H_ + h)*T_ + t)*R_ + r] = val;
                } else {
                    const int c = col - 1024; const int h = c >> 6, dh = c & 63;
                    v[((size_t)(b*H_ + h)*T_ + t)*DH_ + dh] = val;
                }
            }
        }
    }
}

// ---------------------------------------------------------------------------
// Kernel 1b: transpose v (B,H,T,DH) -> v_t (B,H,DH,T), bf16.
// ---------------------------------------------------------------------------
__global__ __launch_bounds__(256) void transpose_v(
    const u16* __restrict__ v, u16* __restrict__ v_t)
{
    __shared__ __align__(16) u16 tile[64 * 72];
    const int tid = threadIdx.x;
    const int st  = blockIdx.x;
    const int bh  = blockIdx.y;
    #pragma unroll
    for (int p = 0; p < 2; ++p) {
        const int e = tid + p * 256;
        const int r = e >> 3, ch = e & 7;
        uint4 w = *(const uint4*)(v + ((size_t)bh * T_ + st*64 + r) * DH_ + ch*8);
        *(uint4*)&tile[r * 72 + ch*8] = w;
    }
    __syncthreads();
    #pragma unroll
    for (int p = 0; p < 2; ++p) {
        const int e = tid + p * 256;
        const int d = e >> 3, ch = e & 7;
        u16 tmp[8];
        #pragma unroll
        for (int j = 0; j < 8; ++j) tmp[j] = tile[(ch*8 + j) * 72 + d];
        *(uint4*)(v_t + ((size_t)(bh * DH_ + d)) * T_ + st*64 + ch*8) = *(uint4*)tmp;
    }
}

// ---------------------------------------------------------------------------
// Kernel 2: MFMA flash attention (bf16 in, fp32 softmax/accum, bf16 y out).
// ---------------------------------------------------------------------------
__global__ __launch_bounds__(256) void attn_kernel(
    const u16* __restrict__ ql, const u16* __restrict__ kl,
    const u16* __restrict__ v_t, u16* __restrict__ y)
{
    __shared__ __align__(16) u16 qls[64 * 40];
    __shared__ __align__(16) u16 kls[64 * 40];
    __shared__ __align__(16) u16 vsT[64 * 72];
    __shared__ __align__(16) u16 Ps [64 * 72];

    const int tid  = threadIdx.x;
    const int lane = tid & 63;
    const int w    = tid >> 6;
    const int n16  = lane & 15;
    const int q4   = lane >> 4;
    const int qt   = 31 - (int)blockIdx.x;  // heavy q-tiles first
    const int bh   = blockIdx.y;
    const int t0   = qt * 64;

    {
        const int e = tid;
        const int r = e >> 2, ch = e & 3;
        uint4 x = *(const uint4*)(ql + ((size_t)bh * T_ + t0 + r) * R_ + ch*8);
        *(uint4*)&qls[r * 40 + ch*8] = x;
    }
    bhalf8 aq = *(const bhalf8*)&qls[(w*16 + n16) * 40 + q4*8];

    float m[4], l[4];
    floatx4 O[4];
    #pragma unroll
    for (int r = 0; r < 4; ++r) { m[r] = NEG_; l[r] = 0.f; }
    #pragma unroll
    for (int c = 0; c < 4; ++c) O[c] = (floatx4)(0.f);

    const int nt = qt + 1;
    for (int it = 0; it < nt; ++it) {
        const int s0 = it * 64;
        __syncthreads();
        {
            const int e = tid;
            const int r = e >> 2, ch = e & 3;
            uint4 x = *(const uint4*)(kl + ((size_t)bh * T_ + s0 + r) * R_ + ch*8);
            *(uint4*)&kls[r * 40 + ch*8] = x;
        }
        #pragma unroll
        for (int p = 0; p < 2; ++p) {
            const int e = tid + p * 256;
            const int d = e >> 3, ch = e & 7;
            uint4 x = *(const uint4*)(v_t + ((size_t)(bh * DH_ + d)) * T_ + s0 + ch*8);
            *(uint4*)&vsT[d * 72 + ch*8] = x;
        }
        __syncthreads();

        floatx4 Sc[4];
        #pragma unroll
        for (int c = 0; c < 4; ++c) {
            bhalf8 bk = *(const bhalf8*)&kls[(16*c + n16) * 40 + q4*8];
            Sc[c] = __builtin_amdgcn_mfma_f32_16x16x32_bf16(aq, bk, (floatx4)(0.f), 0, 0, 0);
        }

        if (it == nt - 1) {
            const int trow = w*16 + q4*4;
            #pragma unroll
            for (int c = 0; c < 4; ++c) {
                const int s = 16*c + n16;
                #pragma unroll
                for (int r = 0; r < 4; ++r)
                    if (s > trow + r) Sc[c][r] = NEG_;
            }
        }

        float rmax[4];
        #pragma unroll
        for (int r = 0; r < 4; ++r)
            rmax[r] = fmaxf(fmaxf(Sc[0][r], Sc[1][r]), fmaxf(Sc[2][r], Sc[3][r]));
        #pragma unroll
        for (int off = 1; off <= 8; off <<= 1)
            #pragma unroll
            for (int r = 0; r < 4; ++r)
                rmax[r] = fmaxf(rmax[r], __shfl_xor(rmax[r], off, 64));

        float alpha[4], rsum[4];
        float P[4][4];
        #pragma unroll
        for (int r = 0; r < 4; ++r) {
            const float mn = fmaxf(m[r], rmax[r]);
            alpha[r] = __expf(m[r] - mn);
            m[r] = mn;
            float s = 0.f;
            #pragma unroll
            for (int c = 0; c < 4; ++c) {
                P[c][r] = __expf(Sc[c][r] - mn);
                s += P[c][r];
            }
            rsum[r] = s;
        }
        #pragma unroll
        for (int off = 1; off <= 8; off <<= 1)
            #pragma unroll
            for (int r = 0; r < 4; ++r)
                rsum[r] += __shfl_xor(rsum[r], off, 64);
        #pragma unroll
        for (int r = 0; r < 4; ++r) l[r] = l[r] * alpha[r] + rsum[r];
        #pragma unroll
        for (int c = 0; c < 4; ++c)
            #pragma unroll
            for (int r = 0; r < 4; ++r)
                O[c][r] *= alpha[r];

        #pragma unroll
        for (int c = 0; c < 4; ++c)
            #pragma unroll
            for (int r = 0; r < 4; ++r)
                Ps[(w*16 + q4*4 + r) * 72 + 16*c + n16] = tob(P[c][r]);

        bhalf8 pa0 = *(const bhalf8*)&Ps[(w*16 + n16) * 72 +  0 + q4*8];
        bhalf8 pa1 = *(const bhalf8*)&Ps[(w*16 + n16) * 72 + 32 + q4*8];
        #pragma unroll
        for (int c = 0; c < 4; ++c) {
            bhalf8 bv0 = *(const bhalf8*)&vsT[(16*c + n16) * 72 +  0 + q4*8];
            bhalf8 bv1 = *(const bhalf8*)&vsT[(16*c + n16) * 72 + 32 + q4*8];
            O[c] = __builtin_amdgcn_mfma_f32_16x16x32_bf16(pa0, bv0, O[c], 0, 0, 0);
            O[c] = __builtin_amdgcn_mfma_f32_16x16x32_bf16(pa1, bv1, O[c], 0, 0, 0);
        }
    }

    // epilogue -> bf16 y
    const int b = bh >> 4, h = bh & 15;
    #pragma unroll
    for (int r = 0; r < 4; ++r) {
        const float rl = 1.0f / l[r];
        const int t = t0 + w*16 + q4*4 + r;
        #pragma unroll
        for (int c = 0; c < 4; ++c)
            y[((size_t)b * T_ + t) * D_ + h * DH_ + 16*c + n16] = tob(O[c][r] * rl);
    }
}

// ---------------------------------------------------------------------------
// Kernel 3: MFMA out-gemm  yb(4096,1024) @ WoT^T -> out fp32 (4096,1024).
// Same structure as gemm1_mfma, N=1024.
// ---------------------------------------------------------------------------
__global__ __launch_bounds__(256) void out_gemm_mfma(
    const u16* __restrict__ yb, const u16* __restrict__ WoT,
    float* __restrict__ out)
{
    __shared__ __align__(16) u16 As[128 * 72];
    __shared__ __align__(16) u16 Bs[128 * 72];
    const int tid  = threadIdx.x;
    const int lane = tid & 63;
    const int w    = tid >> 6;
    const int n16  = lane & 15;
    const int q4   = lane >> 4;
    const int wx   = w & 1;
    const int wy   = w >> 1;
    const int bm   = blockIdx.y * 128;
    const int bn   = blockIdx.x * 128;

    floatx4 acc[4][4];
    #pragma unroll
    for (int i = 0; i < 4; ++i)
        #pragma unroll
        for (int j = 0; j < 4; ++j) acc[i][j] = (floatx4)(0.f);

    for (int kt = 0; kt < D_; kt += 64) {
        #pragma unroll
        for (int p = 0; p < 4; ++p) {
            const int e = tid + p * 256;
            const int r = e >> 3, ch = e & 7;
            uint4 wa = *(const uint4*)(yb  + (size_t)(bm + r) * D_ + kt + ch*8);
            uint4 wb = *(const uint4*)(WoT + (size_t)(bn + r) * D_ + kt + ch*8);
            *(uint4*)&As[r * 72 + ch*8] = wa;
            *(uint4*)&Bs[r * 72 + ch*8] = wb;
        }
        __syncthreads();
        #pragma unroll
        for (int kk = 0; kk < 2; ++kk) {
            bhalf8 a[4], b[4];
            #pragma unroll
            for (int mi = 0; mi < 4; ++mi)
                a[mi] = *(const bhalf8*)&As[(wy*64 + mi*16 + n16) * 72 + kk*32 + q4*8];
            #pragma unroll
            for (int ni = 0; ni < 4; ++ni)
                b[ni] = *(const bhalf8*)&Bs[(wx*64 + ni*16 + n16) * 72 + kk*32 + q4*8];
            #pragma unroll
            for (int mi = 0; mi < 4; ++mi)
                #pragma unroll
                for (int ni = 0; ni < 4; ++ni)
                    acc[mi][ni] = __builtin_amdgcn_mfma_f32_16x16x32_bf16(
                        a[mi], b[ni], acc[mi][ni], 0, 0, 0);
        }
        __syncthreads();
    }

    #pragma unroll
    for (int mi = 0; mi < 4; ++mi) {
        #pragma unroll
        for (int rr = 0; rr < 4; ++rr) {
            const int row = bm + wy*64 + mi*16 + q4*4 + rr;
            #pragma unroll
            for (int ni = 0; ni < 4; ++ni) {
                const int col = bn + wx*64 + ni*16 + n16;
                out[(size_t)row * D_ + col] = acc[mi][ni][rr];
            }
        }
    }
}

// ---------------------------------------------------------------------------
extern "C" void kernel_launch(void* const* d_in, const int* in_sizes, int n_in,
                              void* d_out, int out_size, void* d_ws, size_t ws_size,
                              hipStream_t stream)
{
    (void)out_size; (void)ws_size;
    const void* in_x = nullptr; const void* in_wqkv = nullptr;
    const void* in_wq = nullptr; const void* in_wk = nullptr;
    const void* in_core = nullptr; const void* in_wo = nullptr;
    for (int i = 0; i < n_in; ++i) {
        const int s = in_sizes[i];
        if      (s == BT_*D_)     { if (!in_x)    in_x    = d_in[i]; }
        else if (s == D_*3*D_)    { if (!in_wqkv) in_wqkv = d_in[i]; }
        else if (s == H_*DH_*R_)  { if (!in_wq)   in_wq   = d_in[i]; else if (!in_wk) in_wk = d_in[i]; }
        else if (s == H_*R_)      { if (!in_core) in_core = d_in[i]; }
        else if (s == D_*D_)      { if (!in_wo)   in_wo   = d_in[i]; }
    }
    if (!in_x)    in_x    = d_in[0];
    if (!in_wqkv) in_wqkv = d_in[1];
    if (!in_wq)   in_wq   = d_in[2];
    if (!in_wk)   in_wk   = d_in[3];
    if (!in_core) in_core = d_in[4];
    if (!in_wo)   in_wo   = d_in[5];

    float* out = (float*)d_out;

    char* ws    = (char*)d_ws;
    int*  flag  = (int*)(ws + WSB_FLAG);
    u16*  xb    = (u16*)(ws + WSB_XB);
    u16*  Wcat  = (u16*)(ws + WSB_WCAT);
    u16*  WcatT = (u16*)(ws + WSB_WCATT);
    u16*  ql    = (u16*)(ws + WSB_QL);
    u16*  kl    = (u16*)(ws + WSB_KL);
    u16*  v     = (u16*)(ws + WSB_V);
    u16*  v_t   = (u16*)(ws + WSB_VT);
    u16*  yb    = (u16*)(ws + WSB_YB);
    u16*  WoT   = (u16*)(ws + WSB_WOT);

    detect_dtype<<<1, 64, 0, stream>>>((const u32*)in_x, flag);
    convert_x<<<2048, 256, 0, stream>>>(in_x, xb, flag);
    fold_weights<<<(D_*512)/256, 256, 0, stream>>>(in_wqkv, in_wq, in_wk, in_core, Wcat, flag);
    convert_wv<<<(D_*D_)/256, 256, 0, stream>>>(in_wqkv, Wcat, flag);
    transpose_b16<<<dim3(2048/64, D_/64), 256, 0, stream>>>(Wcat, WcatT, D_, 2048);
    convert_woT<<<dim3(D_/64, D_/64), 256, 0, stream>>>(in_wo, WoT, flag);
    gemm1_mfma<<<dim3(2048/128, BT_/128), 256, 0, stream>>>(xb, WcatT, ql, kl, v);
    transpose_v<<<dim3(T_/64, BH_), 256, 0, stream>>>(v, v_t);
    attn_kernel<<<dim3(T_/64, BH_), 256, 0, stream>>>(ql, kl, v_t, yb);
    out_gemm_mfma<<<dim3(D_/128, BT_/128), 256, 0, stream>>>(yb, WoT, out);
}

// Round 8
// 247.408 us; speedup vs baseline: 7.3010x; 1.1681x over previous
//
#include <hip/hip_runtime.h>
#include <hip/hip_bf16.h>

// Established rounds 0-7: inputs fp32 (detector=insurance), output fp32.
// R5: fp32 VALU attn spills+LDS-bound -> MFMA. R6: fp32 GEMMs -> MFMA.
// R7: attn latency-bound (Mfma 4%, occ 14%) -> 128-wide s-tiles + reg
// prefetch + Ps bank-conflict fix + L2-local grid; pipeline consolidation.
#define B_  2
#define T_  2048
#define D_  1024
#define H_  16
#define DH_ 64
#define R_  32
#define BT_ (B_*T_)          // 4096
#define BH_ (B_*H_)          // 32

typedef unsigned short u16;
typedef unsigned int   u32;
typedef __attribute__((ext_vector_type(8))) short bhalf8;   // 8 bf16 = 4 VGPRs
typedef __attribute__((ext_vector_type(4))) float floatx4;  // MFMA C/D

// Workspace layout (bytes). Total ~38.3 MB.
#define WSB_FLAG  0
#define WSB_XB    256                        // bf16 x     (4096,1024)  8 MB
#define WSB_WCATT (WSB_XB    + 8388608)      // bf16 WcatT (2048,1024)  4 MB
#define WSB_QL    (WSB_WCATT + 4194304)      // bf16 (B,H,T,R)          4 MB
#define WSB_KL    (WSB_QL    + 4194304)      // bf16 (B,H,T,R)          4 MB
#define WSB_VT    (WSB_KL    + 4194304)      // bf16 (B,H,DH,T)         8 MB
#define WSB_YB    (WSB_VT    + 8388608)      // bf16 y     (B,T,D)      8 MB
#define WSB_WOT   (WSB_YB    + 8388608)      // bf16 WoT   (1024,1024)  2 MB

#define NEG_ -1.0e30f

__device__ __forceinline__ float bfs(u16 s) {
    union { u32 i; float f; } w; w.i = ((u32)s) << 16; return w.f;
}
__device__ __forceinline__ u16 tob(float f) {
    __hip_bfloat16 h = __float2bfloat16(f);   // RNE
    return *(u16*)&h;
}
__device__ __forceinline__ u32 pack2(float a, float b) {
    return (u32)tob(a) | ((u32)tob(b) << 16);
}

// ---------------------------------------------------------------------------
// Kernel D: detect input dtype (1 = bf16, 0 = fp32) — insurance only.
// ---------------------------------------------------------------------------
__global__ __launch_bounds__(64) void detect_dtype(const u32* __restrict__ xw,
                                                   int* __restrict__ flag)
{
    const int tid = threadIdx.x;
    int hits = 0;
    for (int i = tid; i < 512; i += 64) {
        const u32 w = xw[i];
        const u32 h = w & 0xFFFFu;
        const u32 e = (h >> 7) & 0xFFu;
        if (h == 0u || (e >= 100u && e <= 150u)) ++hits;
    }
    #pragma unroll
    for (int off = 32; off; off >>= 1) hits += __shfl_down(hits, off, 64);
    if (tid == 0) *flag = (hits >= 300) ? 1 : 0;
}

// ---------------------------------------------------------------------------
// Kernel C: x -> xb bf16 (8 elems/thread).
// ---------------------------------------------------------------------------
__global__ __launch_bounds__(256) void convert_x(
    const void* __restrict__ x, u16* __restrict__ xb,
    const int* __restrict__ flag)
{
    const int isbf = *flag;
    const int e = blockIdx.x * 256 + threadIdx.x;  // over 524288 (x8 elems)
    if (isbf) {
        ((uint4*)xb)[e] = ((const uint4*)x)[e];
    } else {
        float4 a0 = ((const float4*)x)[2*e];
        float4 a1 = ((const float4*)x)[2*e + 1];
        uint4 o;
        o.x = pack2(a0.x, a0.y); o.y = pack2(a0.z, a0.w);
        o.z = pack2(a1.x, a1.y); o.w = pack2(a1.z, a1.w);
        ((uint4*)xb)[e] = o;
    }
}

// ---------------------------------------------------------------------------
// Kernel 0: fold LSR weights (+ core + 1/sqrt(R)) -> WcatT rows 0..1023,
// written TRANSPOSED + coalesced (8 d per thread, uint4 stores).
// WcatT[hr][d]     = sum_dh Wqkv[d][h*64+dh]      * Wq_lsr[h][dh][r] * core * scale
// WcatT[512+hr][d] = sum_dh Wqkv[d][D + h*64+dh]  * Wk_lsr[h][dh][r]
// ---------------------------------------------------------------------------
__global__ __launch_bounds__(256) void fold_weightsT(
    const void* __restrict__ Wqkv, const void* __restrict__ Wq_lsr,
    const void* __restrict__ Wk_lsr, const void* __restrict__ core,
    u16* __restrict__ WcatT, const int* __restrict__ flag)
{
    const int isbf = *flag;
    const int gid = blockIdx.x * 256 + threadIdx.x;  // 0..65535
    const int d0  = (gid & 127) * 8;
    const int hr  = gid >> 7;                        // 0..511
    const int h   = hr >> 5;
    const int r   = hr & 31;
    float sq[8], sk[8];
    #pragma unroll
    for (int j = 0; j < 8; ++j) { sq[j] = 0.f; sk[j] = 0.f; }
    float cc;
    if (isbf) {
        const u16* W  = (const u16*)Wqkv;
        const u16* Aq = (const u16*)Wq_lsr;
        const u16* Ak = (const u16*)Wk_lsr;
        #pragma unroll 1
        for (int j = 0; j < 8; ++j) {
            const u16* wcol = W + (size_t)(d0 + j) * (3*D_) + h * DH_;
            for (int dh = 0; dh < DH_; ++dh) {
                sq[j] = fmaf(bfs(wcol[dh]),      bfs(Aq[(h*DH_+dh)*R_ + r]), sq[j]);
                sk[j] = fmaf(bfs(wcol[dh + D_]), bfs(Ak[(h*DH_+dh)*R_ + r]), sk[j]);
            }
        }
        cc = bfs(((const u16*)core)[h * R_ + r]);
    } else {
        const float* W  = (const float*)Wqkv;
        const float* Aq = (const float*)Wq_lsr;
        const float* Ak = (const float*)Wk_lsr;
        #pragma unroll 1
        for (int j = 0; j < 8; ++j) {
            const float* wcol = W + (size_t)(d0 + j) * (3*D_) + h * DH_;
            for (int dh = 0; dh < DH_; ++dh) {
                sq[j] = fmaf(wcol[dh],      Aq[(h*DH_+dh)*R_ + r], sq[j]);
                sk[j] = fmaf(wcol[dh + D_], Ak[(h*DH_+dh)*R_ + r], sk[j]);
            }
        }
        cc = ((const float*)core)[h * R_ + r];
    }
    const float scale = 0.17677669529663687f;  // 1/sqrt(32)
    uint4 oq, ok;
    oq.x = pack2(sq[0]*cc*scale, sq[1]*cc*scale);
    oq.y = pack2(sq[2]*cc*scale, sq[3]*cc*scale);
    oq.z = pack2(sq[4]*cc*scale, sq[5]*cc*scale);
    oq.w = pack2(sq[6]*cc*scale, sq[7]*cc*scale);
    ok.x = pack2(sk[0], sk[1]); ok.y = pack2(sk[2], sk[3]);
    ok.z = pack2(sk[4], sk[5]); ok.w = pack2(sk[6], sk[7]);
    *(uint4*)(WcatT + (size_t)hr * D_ + d0)         = oq;
    *(uint4*)(WcatT + (size_t)(512 + hr) * D_ + d0) = ok;
}

// ---------------------------------------------------------------------------
// Kernel T: generic transposing convert (fp32/bf16 -> bf16), 64x64 tiles.
// dst[dstRowOff + j][i] = src[i][srcColOff + j], src logical 1024x1024.
// ---------------------------------------------------------------------------
__global__ __launch_bounds__(256) void convert_T(
    const void* __restrict__ src, u16* __restrict__ dst,
    int srcStride, int srcColOff, int dstRowOff, const int* __restrict__ flag)
{
    __shared__ __align__(16) u16 tile[64 * 72];
    const int isbf = *flag;
    const int tid = threadIdx.x;
    const int j0  = blockIdx.x * 64;   // src col -> dst row
    const int i0  = blockIdx.y * 64;   // src row -> dst col
    #pragma unroll
    for (int p = 0; p < 2; ++p) {
        const int e = tid + p * 256;
        const int r = e >> 3, ch = e & 7;
        if (isbf) {
            uint4 w = *(const uint4*)((const u16*)src + (size_t)(i0 + r) * srcStride + srcColOff + j0 + ch*8);
            *(uint4*)&tile[r * 72 + ch*8] = w;
        } else {
            const float* s = (const float*)src + (size_t)(i0 + r) * srcStride + srcColOff + j0 + ch*8;
            float4 a0 = *(const float4*)s;
            float4 a1 = *(const float4*)(s + 4);
            uint4 o;
            o.x = pack2(a0.x, a0.y); o.y = pack2(a0.z, a0.w);
            o.z = pack2(a1.x, a1.y); o.w = pack2(a1.z, a1.w);
            *(uint4*)&tile[r * 72 + ch*8] = o;
        }
    }
    __syncthreads();
    #pragma unroll
    for (int p = 0; p < 2; ++p) {
        const int e = tid + p * 256;
        const int c = e >> 3, ch = e & 7;
        u16 tmp[8];
        #pragma unroll
        for (int j = 0; j < 8; ++j) tmp[j] = tile[(ch*8 + j) * 72 + c];
        *(uint4*)(dst + (size_t)(dstRowOff + j0 + c) * D_ + i0 + ch*8) = *(uint4*)tmp;
    }
}

// ---------------------------------------------------------------------------
// Kernel 1: MFMA gemm1  xb(4096,1024) @ WcatT^T -> ql/kl scatter + v_t direct.
// 128x128 tile, BK=64, 4 waves 2x2, each wave 64x64 (16 MFMA accs).
// Section per block is uniform (128-wide sections of the 2048 cols).
// ---------------------------------------------------------------------------
__global__ __launch_bounds__(256) void gemm1_mfma(
    const u16* __restrict__ xb, const u16* __restrict__ WcatT,
    u16* __restrict__ ql, u16* __restrict__ kl, u16* __restrict__ v_t)
{
    __shared__ __align__(16) u16 As[128 * 72];
    __shared__ __align__(16) u16 Bs[128 * 72];
    const int tid  = threadIdx.x;
    const int lane = tid & 63;
    const int w    = tid >> 6;
    const int n16  = lane & 15;
    const int q4   = lane >> 4;
    const int wx   = w & 1;          // n-half
    const int wy   = w >> 1;         // m-half
    const int bm   = blockIdx.y * 128;
    const int bn   = blockIdx.x * 128;

    floatx4 acc[4][4];
    #pragma unroll
    for (int i = 0; i < 4; ++i)
        #pragma unroll
        for (int j = 0; j < 4; ++j) acc[i][j] = (floatx4)(0.f);

    for (int kt = 0; kt < D_; kt += 64) {
        #pragma unroll
        for (int p = 0; p < 4; ++p) {
            const int e = tid + p * 256;       // 0..1023
            const int r = e >> 3, ch = e & 7;
            uint4 wa = *(const uint4*)(xb    + (size_t)(bm + r) * D_ + kt + ch*8);
            uint4 wb = *(const uint4*)(WcatT + (size_t)(bn + r) * D_ + kt + ch*8);
            *(uint4*)&As[r * 72 + ch*8] = wa;
            *(uint4*)&Bs[r * 72 + ch*8] = wb;
        }
        __syncthreads();
        #pragma unroll
        for (int kk = 0; kk < 2; ++kk) {
            bhalf8 a[4], b[4];
            #pragma unroll
            for (int mi = 0; mi < 4; ++mi)
                a[mi] = *(const bhalf8*)&As[(wy*64 + mi*16 + n16) * 72 + kk*32 + q4*8];
            #pragma unroll
            for (int ni = 0; ni < 4; ++ni)
                b[ni] = *(const bhalf8*)&Bs[(wx*64 + ni*16 + n16) * 72 + kk*32 + q4*8];
            #pragma unroll
            for (int mi = 0; mi < 4; ++mi)
                #pragma unroll
                for (int ni = 0; ni < 4; ++ni)
                    acc[mi][ni] = __builtin_amdgcn_mfma_f32_16x16x32_bf16(
                        a[mi], b[ni], acc[mi][ni], 0, 0, 0);
        }
        __syncthreads();
    }

    if (bn < 1024) {
        // ql / kl scalar scatter (block section-uniform; per-col test cheap)
        #pragma unroll
        for (int mi = 0; mi < 4; ++mi) {
            #pragma unroll
            for (int rr = 0; rr < 4; ++rr) {
                const int row = bm + wy*64 + mi*16 + q4*4 + rr;
                const int b   = row >> 11;
                const int t   = row & (T_ - 1);
                #pragma unroll
                for (int ni = 0; ni < 4; ++ni) {
                    const int col = bn + wx*64 + ni*16 + n16;
                    const u16 val = tob(acc[mi][ni][rr]);
                    if (col < 512) {
                        const int h = col >> 5, r = col & 31;
                        ql[((size_t)(b*H_ + h)*T_ + t)*R_ + r] = val;
                    } else {
                        const int c = col - 512; const int h = c >> 5, r = c & 31;
                        kl[((size_t)(b*H_ + h)*T_ + t)*R_ + r] = val;
                    }
                }
            }
        }
    } else {
        // v: write v_t (B,H,DH,T) directly — 4 consecutive t pack into 8B
        #pragma unroll
        for (int mi = 0; mi < 4; ++mi) {
            const int row0 = bm + wy*64 + mi*16 + q4*4;
            const int b = row0 >> 11;
            const int t = row0 & (T_ - 1);
            #pragma unroll
            for (int ni = 0; ni < 4; ++ni) {
                const int c = bn - 1024 + wx*64 + ni*16 + n16;
                const int h = c >> 6, dh = c & 63;
                uint2 o;
                o.x = pack2(acc[mi][ni][0], acc[mi][ni][1]);
                o.y = pack2(acc[mi][ni][2], acc[mi][ni][3]);
                *(uint2*)(v_t + ((size_t)(b*H_ + h) * DH_ + dh) * T_ + t) = o;
            }
        }
    }
}

// ---------------------------------------------------------------------------
// Kernel 2: MFMA flash attention — 64-row q-tile x 128-col s-tiles.
// 4 waves; wave w owns q-rows w*16..+15. Per s-tile: 8 QK MFMA + 16 PV MFMA
// per wave, distributed online softmax (16-lane shfl_xor), Ps with
// (q4<->r) slot transpose @ stride 144 u16 (conflict-free writes).
// Register double-buffer prefetch of kl/v overlaps HBM/L2 latency w/ compute.
// Grid: (bh, qtIdx) -> same-qt blocks contiguous; bh mod 8 pins XCD L2 set.
// ---------------------------------------------------------------------------
__global__ __launch_bounds__(256, 2) void attn_kernel(
    const u16* __restrict__ ql, const u16* __restrict__ kl,
    const u16* __restrict__ v_t, u16* __restrict__ y)
{
    __shared__ __align__(16) u16 qls[64 * 40];     //  5120 B
    __shared__ __align__(16) u16 kls[128 * 40];    // 10240 B
    __shared__ __align__(16) u16 vsT[64 * 136];    // 17408 B
    __shared__ __align__(16) u16 Ps [64 * 144];    // 18432 B  (sum 51200)

    const int tid  = threadIdx.x;
    const int lane = tid & 63;
    const int w    = tid >> 6;
    const int n16  = lane & 15;
    const int q4   = lane >> 4;
    const int bh   = blockIdx.x;
    const int qt   = 31 - (int)blockIdx.y;   // heavy q-tiles first
    const int t0   = qt * 64;
    const int nt   = (qt + 2) >> 1;          // # of 128-wide s-tiles

    // stage qls (wave-private rows: tid>>2 in [w*16, w*16+16))
    {
        const int r = tid >> 2, ch = tid & 3;
        uint4 x = *(const uint4*)(ql + ((size_t)bh * T_ + t0 + r) * R_ + ch*8);
        *(uint4*)&qls[r * 40 + ch*8] = x;
    }
    bhalf8 aq = *(const bhalf8*)&qls[(w*16 + n16) * 40 + q4*8];

    const u16* klb = kl  + (size_t)bh * T_ * R_;
    const u16* vtb = v_t + (size_t)bh * DH_ * T_;
    const int rk = tid >> 2, ck = (tid & 3) * 8;      // k staging coords
    const int dv = tid >> 4, cv = (tid & 15) * 8;     // v staging coords

    // prologue prefetch (tile 0)
    uint4 kc0 = *(const uint4*)(klb + (size_t)(rk     ) * R_ + ck);
    uint4 kc1 = *(const uint4*)(klb + (size_t)(rk + 64) * R_ + ck);
    uint4 vc0 = *(const uint4*)(vtb + (size_t)(dv     ) * T_ + cv);
    uint4 vc1 = *(const uint4*)(vtb + (size_t)(dv + 16) * T_ + cv);
    uint4 vc2 = *(const uint4*)(vtb + (size_t)(dv + 32) * T_ + cv);
    uint4 vc3 = *(const uint4*)(vtb + (size_t)(dv + 48) * T_ + cv);
    uint4 kn0 = kc0, kn1 = kc1, vn0 = vc0, vn1 = vc1, vn2 = vc2, vn3 = vc3;

    float m[4], l[4];
    floatx4 O[4];
    #pragma unroll
    for (int r = 0; r < 4; ++r) { m[r] = NEG_; l[r] = 0.f; }
    #pragma unroll
    for (int c = 0; c < 4; ++c) O[c] = (floatx4)(0.f);

    for (int it = 0; it < nt; ++it) {
        const int s0 = it * 128;
        __syncthreads();   // prev tile's readers of kls/vsT done
        // store current tile to LDS
        *(uint4*)&kls[(rk     ) * 40 + ck] = kc0;
        *(uint4*)&kls[(rk + 64) * 40 + ck] = kc1;
        *(uint4*)&vsT[(dv     ) * 136 + cv] = vc0;
        *(uint4*)&vsT[(dv + 16) * 136 + cv] = vc1;
        *(uint4*)&vsT[(dv + 32) * 136 + cv] = vc2;
        *(uint4*)&vsT[(dv + 48) * 136 + cv] = vc3;
        // prefetch next tile (flies during compute below)
        if (it + 1 < nt) {
            const int s1 = s0 + 128;
            kn0 = *(const uint4*)(klb + (size_t)(s1 + rk     ) * R_ + ck);
            kn1 = *(const uint4*)(klb + (size_t)(s1 + rk + 64) * R_ + ck);
            vn0 = *(const uint4*)(vtb + (size_t)(dv     ) * T_ + s1 + cv);
            vn1 = *(const uint4*)(vtb + (size_t)(dv + 16) * T_ + s1 + cv);
            vn2 = *(const uint4*)(vtb + (size_t)(dv + 32) * T_ + s1 + cv);
            vn3 = *(const uint4*)(vtb + (size_t)(dv + 48) * T_ + s1 + cv);
        }
        __syncthreads();

        // QK: 8 col-subtiles
        floatx4 Sc[8];
        #pragma unroll
        for (int c = 0; c < 8; ++c) {
            bhalf8 bk = *(const bhalf8*)&kls[(16*c + n16) * 40 + q4*8];
            Sc[c] = __builtin_amdgcn_mfma_f32_16x16x32_bf16(aq, bk, (floatx4)(0.f), 0, 0, 0);
        }

        // causal mask (only last tile contains the diagonal)
        if (it == nt - 1) {
            const int tg = t0 + w*16 + q4*4;
            #pragma unroll
            for (int c = 0; c < 8; ++c) {
                const int sg = s0 + 16*c + n16;
                #pragma unroll
                for (int r = 0; r < 4; ++r)
                    if (sg > tg + r) Sc[c][r] = NEG_;
            }
        }

        // distributed online softmax (rows = q4*4+r; reduce over 16 lanes)
        float rmax[4];
        #pragma unroll
        for (int r = 0; r < 4; ++r) {
            float a0 = fmaxf(fmaxf(Sc[0][r], Sc[1][r]), fmaxf(Sc[2][r], Sc[3][r]));
            float a1 = fmaxf(fmaxf(Sc[4][r], Sc[5][r]), fmaxf(Sc[6][r], Sc[7][r]));
            rmax[r] = fmaxf(a0, a1);
        }
        #pragma unroll
        for (int off = 1; off <= 8; off <<= 1)
            #pragma unroll
            for (int r = 0; r < 4; ++r)
                rmax[r] = fmaxf(rmax[r], __shfl_xor(rmax[r], off, 64));

        float alpha[4], rsum[4];
        #pragma unroll
        for (int r = 0; r < 4; ++r) {
            const float mn = fmaxf(m[r], rmax[r]);
            alpha[r] = __expf(m[r] - mn);
            m[r] = mn;
            rsum[r] = 0.f;
        }
        #pragma unroll
        for (int c = 0; c < 8; ++c)
            #pragma unroll
            for (int r = 0; r < 4; ++r) {
                const float p = __expf(Sc[c][r] - m[r]);
                Sc[c][r] = p;
                rsum[r] += p;
            }
        #pragma unroll
        for (int off = 1; off <= 8; off <<= 1)
            #pragma unroll
            for (int r = 0; r < 4; ++r)
                rsum[r] += __shfl_xor(rsum[r], off, 64);
        #pragma unroll
        for (int r = 0; r < 4; ++r) l[r] = l[r] * alpha[r] + rsum[r];
        #pragma unroll
        for (int c = 0; c < 4; ++c)
            #pragma unroll
            for (int r = 0; r < 4; ++r)
                O[c][r] *= alpha[r];

        // P -> Ps, slot-transposed rows (q4<->r): write-instr banks {0,8,16,24}
        #pragma unroll
        for (int c = 0; c < 8; ++c)
            #pragma unroll
            for (int r = 0; r < 4; ++r)
                Ps[(w*16 + r*4 + q4) * 144 + 16*c + n16] = tob(Sc[c][r]);

        // PV: O[c2] += P(16x128) @ V(128 x 16-col-block c2); wave-private Ps
        const int slot = w*16 + (n16 & 3)*4 + (n16 >> 2);
        #pragma unroll
        for (int kc = 0; kc < 4; ++kc) {
            bhalf8 pa = *(const bhalf8*)&Ps[slot * 144 + kc*32 + q4*8];
            #pragma unroll
            for (int c2 = 0; c2 < 4; ++c2) {
                bhalf8 bv = *(const bhalf8*)&vsT[(16*c2 + n16) * 136 + kc*32 + q4*8];
                O[c2] = __builtin_amdgcn_mfma_f32_16x16x32_bf16(pa, bv, O[c2], 0, 0, 0);
            }
        }

        // rotate prefetch buffers
        kc0 = kn0; kc1 = kn1; vc0 = vn0; vc1 = vn1; vc2 = vn2; vc3 = vn3;
    }

    // epilogue -> bf16 y
    const int b = bh >> 4, h = bh & 15;
    #pragma unroll
    for (int r = 0; r < 4; ++r) {
        const float rl = 1.0f / l[r];
        const int t = t0 + w*16 + q4*4 + r;
        #pragma unroll
        for (int c2 = 0; c2 < 4; ++c2)
            y[((size_t)b * T_ + t) * D_ + h * DH_ + 16*c2 + n16] = tob(O[c2][r] * rl);
    }
}

// ---------------------------------------------------------------------------
// Kernel 3: MFMA out-gemm  yb(4096,1024) @ WoT^T -> out fp32 (4096,1024).
// ---------------------------------------------------------------------------
__global__ __launch_bounds__(256) void out_gemm_mfma(
    const u16* __restrict__ yb, const u16* __restrict__ WoT,
    float* __restrict__ out)
{
    __shared__ __align__(16) u16 As[128 * 72];
    __shared__ __align__(16) u16 Bs[128 * 72];
    const int tid  = threadIdx.x;
    const int lane = tid & 63;
    const int w    = tid >> 6;
    const int n16  = lane & 15;
    const int q4   = lane >> 4;
    const int wx   = w & 1;
    const int wy   = w >> 1;
    const int bm   = blockIdx.y * 128;
    const int bn   = blockIdx.x * 128;

    floatx4 acc[4][4];
    #pragma unroll
    for (int i = 0; i < 4; ++i)
        #pragma unroll
        for (int j = 0; j < 4; ++j) acc[i][j] = (floatx4)(0.f);

    for (int kt = 0; kt < D_; kt += 64) {
        #pragma unroll
        for (int p = 0; p < 4; ++p) {
            const int e = tid + p * 256;
            const int r = e >> 3, ch = e & 7;
            uint4 wa = *(const uint4*)(yb  + (size_t)(bm + r) * D_ + kt + ch*8);
            uint4 wb = *(const uint4*)(WoT + (size_t)(bn + r) * D_ + kt + ch*8);
            *(uint4*)&As[r * 72 + ch*8] = wa;
            *(uint4*)&Bs[r * 72 + ch*8] = wb;
        }
        __syncthreads();
        #pragma unroll
        for (int kk = 0; kk < 2; ++kk) {
            bhalf8 a[4], b[4];
            #pragma unroll
            for (int mi = 0; mi < 4; ++mi)
                a[mi] = *(const bhalf8*)&As[(wy*64 + mi*16 + n16) * 72 + kk*32 + q4*8];
            #pragma unroll
            for (int ni = 0; ni < 4; ++ni)
                b[ni] = *(const bhalf8*)&Bs[(wx*64 + ni*16 + n16) * 72 + kk*32 + q4*8];
            #pragma unroll
            for (int mi = 0; mi < 4; ++mi)
                #pragma unroll
                for (int ni = 0; ni < 4; ++ni)
                    acc[mi][ni] = __builtin_amdgcn_mfma_f32_16x16x32_bf16(
                        a[mi], b[ni], acc[mi][ni], 0, 0, 0);
        }
        __syncthreads();
    }

    #pragma unroll
    for (int mi = 0; mi < 4; ++mi) {
        #pragma unroll
        for (int rr = 0; rr < 4; ++rr) {
            const int row = bm + wy*64 + mi*16 + q4*4 + rr;
            #pragma unroll
            for (int ni = 0; ni < 4; ++ni) {
                const int col = bn + wx*64 + ni*16 + n16;
                out[(size_t)row * D_ + col] = acc[mi][ni][rr];
            }
        }
    }
}

// ---------------------------------------------------------------------------
extern "C" void kernel_launch(void* const* d_in, const int* in_sizes, int n_in,
                              void* d_out, int out_size, void* d_ws, size_t ws_size,
                              hipStream_t stream)
{
    (void)out_size; (void)ws_size;
    const void* in_x = nullptr; const void* in_wqkv = nullptr;
    const void* in_wq = nullptr; const void* in_wk = nullptr;
    const void* in_core = nullptr; const void* in_wo = nullptr;
    for (int i = 0; i < n_in; ++i) {
        const int s = in_sizes[i];
        if      (s == BT_*D_)     { if (!in_x)    in_x    = d_in[i]; }
        else if (s == D_*3*D_)    { if (!in_wqkv) in_wqkv = d_in[i]; }
        else if (s == H_*DH_*R_)  { if (!in_wq)   in_wq   = d_in[i]; else if (!in_wk) in_wk = d_in[i]; }
        else if (s == H_*R_)      { if (!in_core) in_core = d_in[i]; }
        else if (s == D_*D_)      { if (!in_wo)   in_wo   = d_in[i]; }
    }
    if (!in_x)    in_x    = d_in[0];
    if (!in_wqkv) in_wqkv = d_in[1];
    if (!in_wq)   in_wq   = d_in[2];
    if (!in_wk)   in_wk   = d_in[3];
    if (!in_core) in_core = d_in[4];
    if (!in_wo)   in_wo   = d_in[5];

    float* out = (float*)d_out;

    char* ws    = (char*)d_ws;
    int*  flag  = (int*)(ws + WSB_FLAG);
    u16*  xb    = (u16*)(ws + WSB_XB);
    u16*  WcatT = (u16*)(ws + WSB_WCATT);
    u16*  ql    = (u16*)(ws + WSB_QL);
    u16*  kl    = (u16*)(ws + WSB_KL);
    u16*  v_t   = (u16*)(ws + WSB_VT);
    u16*  yb    = (u16*)(ws + WSB_YB);
    u16*  WoT   = (u16*)(ws + WSB_WOT);

    detect_dtype<<<1, 64, 0, stream>>>((const u32*)in_x, flag);
    convert_x<<<2048, 256, 0, stream>>>(in_x, xb, flag);
    fold_weightsT<<<256, 256, 0, stream>>>(in_wqkv, in_wq, in_wk, in_core, WcatT, flag);
    convert_T<<<dim3(16,16), 256, 0, stream>>>(in_wqkv, WcatT, 3*D_, 2*D_, 1024, flag); // W_v
    convert_T<<<dim3(16,16), 256, 0, stream>>>(in_wo,   WoT,   D_,   0,    0,    flag); // W_o
    gemm1_mfma<<<dim3(16, 32), 256, 0, stream>>>(xb, WcatT, ql, kl, v_t);
    attn_kernel<<<dim3(32, 32), 256, 0, stream>>>(ql, kl, v_t, yb);
    out_gemm_mfma<<<dim3(8, 32), 256, 0, stream>>>(yb, WoT, out);
}

// Round 9
// 231.547 us; speedup vs baseline: 7.8011x; 1.0685x over previous
//
#include <hip/hip_runtime.h>
#include <hip/hip_bf16.h>

// Established rounds 0-8: inputs fp32 (detector=insurance), output fp32.
// R5: fp32 VALU attn spill/LDS-bound -> MFMA. R6: fp32 GEMMs -> MFMA.
// R7: attn 128-wide s-tiles + reg prefetch + conflict-free Ps. R8: fold was
// 68us latency-bound on uncoalesced reads -> per-head MFMA GEMM (B operand is
// k-contiguous in native Wqkv layout); convert_x folded into gemm1 staging.
#define B_  2
#define T_  2048
#define D_  1024
#define H_  16
#define DH_ 64
#define R_  32
#define BT_ (B_*T_)          // 4096
#define BH_ (B_*H_)          // 32

typedef unsigned short u16;
typedef unsigned int   u32;
typedef __attribute__((ext_vector_type(8))) short bhalf8;   // 8 bf16 = 4 VGPRs
typedef __attribute__((ext_vector_type(4))) float floatx4;  // MFMA C/D

// Workspace layout (bytes). Total ~30 MB.
#define WSB_FLAG  0
#define WSB_WCATT 256                        // bf16 WcatT (2048,1024)  4 MB
#define WSB_QL    (WSB_WCATT + 4194304)      // bf16 (B,H,T,R)          4 MB
#define WSB_KL    (WSB_QL    + 4194304)      // bf16 (B,H,T,R)          4 MB
#define WSB_VT    (WSB_KL    + 4194304)      // bf16 (B,H,DH,T)         8 MB
#define WSB_YB    (WSB_VT    + 8388608)      // bf16 y     (B,T,D)      8 MB
#define WSB_WOT   (WSB_YB    + 8388608)      // bf16 WoT   (1024,1024)  2 MB

#define NEG_ -1.0e30f

__device__ __forceinline__ float bfs(u16 s) {
    union { u32 i; float f; } w; w.i = ((u32)s) << 16; return w.f;
}
__device__ __forceinline__ u16 tob(float f) {
    __hip_bfloat16 h = __float2bfloat16(f);   // RNE
    return *(u16*)&h;
}
__device__ __forceinline__ u32 pack2(float a, float b) {
    return (u32)tob(a) | ((u32)tob(b) << 16);
}

// ---------------------------------------------------------------------------
// Kernel D: detect input dtype (1 = bf16, 0 = fp32) — insurance only.
// ---------------------------------------------------------------------------
__global__ __launch_bounds__(64) void detect_dtype(const u32* __restrict__ xw,
                                                   int* __restrict__ flag)
{
    const int tid = threadIdx.x;
    int hits = 0;
    for (int i = tid; i < 512; i += 64) {
        const u32 w = xw[i];
        const u32 h = w & 0xFFFFu;
        const u32 e = (h >> 7) & 0xFFu;
        if (h == 0u || (e >= 100u && e <= 150u)) ++hits;
    }
    #pragma unroll
    for (int off = 32; off; off >>= 1) hits += __shfl_down(hits, off, 64);
    if (tid == 0) *flag = (hits >= 300) ? 1 : 0;
}

// ---------------------------------------------------------------------------
// Kernel 0: fold via MFMA. Per head h: Cq(32x1024) = Aq_h^T(32x64) @ Wq_h(64x1024)
// with m=r, k=dh, n=d. B operand (Wqkv slice) is k-contiguous natively.
// WcatT[h*32+r][d] = Cq * core[h][r] / sqrt(R);  WcatT[512+h*32+r][d] = Ck.
// Block: (d-tile 128, head). 4 waves; wave w owns n-cols w*32..+31.
// ---------------------------------------------------------------------------
__global__ __launch_bounds__(256) void fold_mfma(
    const void* __restrict__ Wqkv, const void* __restrict__ Wq_lsr,
    const void* __restrict__ Wk_lsr, const void* __restrict__ core,
    u16* __restrict__ WcatT, const int* __restrict__ flag)
{
    __shared__ __align__(16) u16 Bq[128 * 72];   // [n=d][k=dh]
    __shared__ __align__(16) u16 Bk[128 * 72];
    __shared__ __align__(16) u16 Aq[32 * 72];    // [m=r][k=dh]
    __shared__ __align__(16) u16 Ak[32 * 72];
    const int isbf = *flag;
    const int tid  = threadIdx.x;
    const int lane = tid & 63;
    const int w    = tid >> 6;
    const int n16  = lane & 15;
    const int q4   = lane >> 4;
    const int h    = blockIdx.y;        // 0..15
    const int d0   = blockIdx.x * 128;  // 0..896

    // stage A_lsr (q,k): 2048 elems each; coalesced over r
    #pragma unroll
    for (int p = 0; p < 8; ++p) {
        const int e  = tid + p * 256;
        const int r  = e & 31, dh = e >> 5;
        float aq, ak;
        if (isbf) {
            aq = bfs(((const u16*)Wq_lsr)[(h*DH_ + dh)*R_ + r]);
            ak = bfs(((const u16*)Wk_lsr)[(h*DH_ + dh)*R_ + r]);
        } else {
            aq = ((const float*)Wq_lsr)[(h*DH_ + dh)*R_ + r];
            ak = ((const float*)Wk_lsr)[(h*DH_ + dh)*R_ + r];
        }
        Aq[r * 72 + dh] = tob(aq);
        Ak[r * 72 + dh] = tob(ak);
    }
    // stage B (Wqkv q/k slices): 128 rows x 64 k, 4-elem chunks, coalesced
    #pragma unroll
    for (int p = 0; p < 8; ++p) {
        const int e  = tid + p * 256;      // 0..2047
        const int n  = e >> 4, ch = e & 15;
        if (isbf) {
            uint2 wq = *(const uint2*)((const u16*)Wqkv + (size_t)(d0+n)*(3*D_) + h*DH_ + ch*4);
            uint2 wk = *(const uint2*)((const u16*)Wqkv + (size_t)(d0+n)*(3*D_) + D_ + h*DH_ + ch*4);
            *(uint2*)&Bq[n * 72 + ch*4] = wq;
            *(uint2*)&Bk[n * 72 + ch*4] = wk;
        } else {
            float4 fq = *(const float4*)((const float*)Wqkv + (size_t)(d0+n)*(3*D_) + h*DH_ + ch*4);
            float4 fk = *(const float4*)((const float*)Wqkv + (size_t)(d0+n)*(3*D_) + D_ + h*DH_ + ch*4);
            uint2 oq, ok;
            oq.x = pack2(fq.x, fq.y); oq.y = pack2(fq.z, fq.w);
            ok.x = pack2(fk.x, fk.y); ok.y = pack2(fk.z, fk.w);
            *(uint2*)&Bq[n * 72 + ch*4] = oq;
            *(uint2*)&Bk[n * 72 + ch*4] = ok;
        }
    }
    __syncthreads();

    floatx4 accq[2][2], acck[2][2];   // [mi][ni]
    #pragma unroll
    for (int mi = 0; mi < 2; ++mi)
        #pragma unroll
        for (int ni = 0; ni < 2; ++ni) { accq[mi][ni] = (floatx4)(0.f); acck[mi][ni] = (floatx4)(0.f); }

    #pragma unroll
    for (int kk = 0; kk < 2; ++kk) {
        bhalf8 aqf[2], akf[2], bqf[2], bkf[2];
        #pragma unroll
        for (int mi = 0; mi < 2; ++mi) {
            aqf[mi] = *(const bhalf8*)&Aq[(mi*16 + n16) * 72 + kk*32 + q4*8];
            akf[mi] = *(const bhalf8*)&Ak[(mi*16 + n16) * 72 + kk*32 + q4*8];
        }
        #pragma unroll
        for (int ni = 0; ni < 2; ++ni) {
            bqf[ni] = *(const bhalf8*)&Bq[(w*32 + ni*16 + n16) * 72 + kk*32 + q4*8];
            bkf[ni] = *(const bhalf8*)&Bk[(w*32 + ni*16 + n16) * 72 + kk*32 + q4*8];
        }
        #pragma unroll
        for (int mi = 0; mi < 2; ++mi)
            #pragma unroll
            for (int ni = 0; ni < 2; ++ni) {
                accq[mi][ni] = __builtin_amdgcn_mfma_f32_16x16x32_bf16(aqf[mi], bqf[ni], accq[mi][ni], 0, 0, 0);
                acck[mi][ni] = __builtin_amdgcn_mfma_f32_16x16x32_bf16(akf[mi], bkf[ni], acck[mi][ni], 0, 0, 0);
            }
    }

    const float scale = 0.17677669529663687f;  // 1/sqrt(32)
    #pragma unroll
    for (int mi = 0; mi < 2; ++mi) {
        #pragma unroll
        for (int rr = 0; rr < 4; ++rr) {
            const int r = mi*16 + q4*4 + rr;
            const float cc = (isbf ? bfs(((const u16*)core)[h*R_ + r])
                                   : ((const float*)core)[h*R_ + r]) * scale;
            #pragma unroll
            for (int ni = 0; ni < 2; ++ni) {
                const int d = d0 + w*32 + ni*16 + n16;
                WcatT[(size_t)(h*R_ + r) * D_ + d]       = tob(accq[mi][ni][rr] * cc);
                WcatT[(size_t)(512 + h*R_ + r) * D_ + d] = tob(acck[mi][ni][rr]);
            }
        }
    }
}

// ---------------------------------------------------------------------------
// Kernel T: generic transposing convert (fp32/bf16 -> bf16), 64x64 tiles.
// dst[dstRowOff + j][i] = src[i][srcColOff + j], src logical 1024 rows.
// ---------------------------------------------------------------------------
__global__ __launch_bounds__(256) void convert_T(
    const void* __restrict__ src, u16* __restrict__ dst,
    int srcStride, int srcColOff, int dstRowOff, const int* __restrict__ flag)
{
    __shared__ __align__(16) u16 tile[64 * 72];
    const int isbf = *flag;
    const int tid = threadIdx.x;
    const int j0  = blockIdx.x * 64;   // src col -> dst row
    const int i0  = blockIdx.y * 64;   // src row -> dst col
    #pragma unroll
    for (int p = 0; p < 2; ++p) {
        const int e = tid + p * 256;
        const int r = e >> 3, ch = e & 7;
        if (isbf) {
            uint4 w = *(const uint4*)((const u16*)src + (size_t)(i0 + r) * srcStride + srcColOff + j0 + ch*8);
            *(uint4*)&tile[r * 72 + ch*8] = w;
        } else {
            const float* s = (const float*)src + (size_t)(i0 + r) * srcStride + srcColOff + j0 + ch*8;
            float4 a0 = *(const float4*)s;
            float4 a1 = *(const float4*)(s + 4);
            uint4 o;
            o.x = pack2(a0.x, a0.y); o.y = pack2(a0.z, a0.w);
            o.z = pack2(a1.x, a1.y); o.w = pack2(a1.z, a1.w);
            *(uint4*)&tile[r * 72 + ch*8] = o;
        }
    }
    __syncthreads();
    #pragma unroll
    for (int p = 0; p < 2; ++p) {
        const int e = tid + p * 256;
        const int c = e >> 3, ch = e & 7;
        u16 tmp[8];
        #pragma unroll
        for (int j = 0; j < 8; ++j) tmp[j] = tile[(ch*8 + j) * 72 + c];
        *(uint4*)(dst + (size_t)(dstRowOff + j0 + c) * D_ + i0 + ch*8) = *(uint4*)tmp;
    }
}

// ---------------------------------------------------------------------------
// Kernel 1: MFMA gemm1  x(4096,1024, fp32/bf16) @ WcatT^T -> ql/kl + v_t.
// 128x128 tile, BK=64, 4 waves 2x2. x converted to bf16 during staging.
// ---------------------------------------------------------------------------
__global__ __launch_bounds__(256) void gemm1_mfma(
    const void* __restrict__ x, const u16* __restrict__ WcatT,
    u16* __restrict__ ql, u16* __restrict__ kl, u16* __restrict__ v_t,
    const int* __restrict__ flag)
{
    __shared__ __align__(16) u16 As[128 * 72];
    __shared__ __align__(16) u16 Bs[128 * 72];
    const int isbf = *flag;
    const int tid  = threadIdx.x;
    const int lane = tid & 63;
    const int w    = tid >> 6;
    const int n16  = lane & 15;
    const int q4   = lane >> 4;
    const int wx   = w & 1;          // n-half
    const int wy   = w >> 1;         // m-half
    const int bm   = blockIdx.y * 128;
    const int bn   = blockIdx.x * 128;

    floatx4 acc[4][4];
    #pragma unroll
    for (int i = 0; i < 4; ++i)
        #pragma unroll
        for (int j = 0; j < 4; ++j) acc[i][j] = (floatx4)(0.f);

    for (int kt = 0; kt < D_; kt += 64) {
        #pragma unroll
        for (int p = 0; p < 4; ++p) {
            const int e = tid + p * 256;       // 0..1023
            const int r = e >> 3, ch = e & 7;
            uint4 wa;
            if (isbf) {
                wa = *(const uint4*)((const u16*)x + (size_t)(bm + r) * D_ + kt + ch*8);
            } else {
                const float* s = (const float*)x + (size_t)(bm + r) * D_ + kt + ch*8;
                float4 a0 = *(const float4*)s;
                float4 a1 = *(const float4*)(s + 4);
                wa.x = pack2(a0.x, a0.y); wa.y = pack2(a0.z, a0.w);
                wa.z = pack2(a1.x, a1.y); wa.w = pack2(a1.z, a1.w);
            }
            uint4 wb = *(const uint4*)(WcatT + (size_t)(bn + r) * D_ + kt + ch*8);
            *(uint4*)&As[r * 72 + ch*8] = wa;
            *(uint4*)&Bs[r * 72 + ch*8] = wb;
        }
        __syncthreads();
        #pragma unroll
        for (int kk = 0; kk < 2; ++kk) {
            bhalf8 a[4], b[4];
            #pragma unroll
            for (int mi = 0; mi < 4; ++mi)
                a[mi] = *(const bhalf8*)&As[(wy*64 + mi*16 + n16) * 72 + kk*32 + q4*8];
            #pragma unroll
            for (int ni = 0; ni < 4; ++ni)
                b[ni] = *(const bhalf8*)&Bs[(wx*64 + ni*16 + n16) * 72 + kk*32 + q4*8];
            #pragma unroll
            for (int mi = 0; mi < 4; ++mi)
                #pragma unroll
                for (int ni = 0; ni < 4; ++ni)
                    acc[mi][ni] = __builtin_amdgcn_mfma_f32_16x16x32_bf16(
                        a[mi], b[ni], acc[mi][ni], 0, 0, 0);
        }
        __syncthreads();
    }

    if (bn < 1024) {
        #pragma unroll
        for (int mi = 0; mi < 4; ++mi) {
            #pragma unroll
            for (int rr = 0; rr < 4; ++rr) {
                const int row = bm + wy*64 + mi*16 + q4*4 + rr;
                const int b   = row >> 11;
                const int t   = row & (T_ - 1);
                #pragma unroll
                for (int ni = 0; ni < 4; ++ni) {
                    const int col = bn + wx*64 + ni*16 + n16;
                    const u16 val = tob(acc[mi][ni][rr]);
                    if (col < 512) {
                        const int h = col >> 5, r = col & 31;
                        ql[((size_t)(b*H_ + h)*T_ + t)*R_ + r] = val;
                    } else {
                        const int c = col - 512; const int h = c >> 5, r = c & 31;
                        kl[((size_t)(b*H_ + h)*T_ + t)*R_ + r] = val;
                    }
                }
            }
        }
    } else {
        // v: write v_t (B,H,DH,T) directly — 4 consecutive t pack into 8B
        #pragma unroll
        for (int mi = 0; mi < 4; ++mi) {
            const int row0 = bm + wy*64 + mi*16 + q4*4;
            const int b = row0 >> 11;
            const int t = row0 & (T_ - 1);
            #pragma unroll
            for (int ni = 0; ni < 4; ++ni) {
                const int c = bn - 1024 + wx*64 + ni*16 + n16;
                const int h = c >> 6, dh = c & 63;
                uint2 o;
                o.x = pack2(acc[mi][ni][0], acc[mi][ni][1]);
                o.y = pack2(acc[mi][ni][2], acc[mi][ni][3]);
                *(uint2*)(v_t + ((size_t)(b*H_ + h) * DH_ + dh) * T_ + t) = o;
            }
        }
    }
}

// ---------------------------------------------------------------------------
// Kernel 2: MFMA flash attention — 64-row q-tile x 128-col s-tiles.
// Register double-buffer prefetch; conflict-free Ps (stride 144, slot xform).
// ---------------------------------------------------------------------------
__global__ __launch_bounds__(256, 2) void attn_kernel(
    const u16* __restrict__ ql, const u16* __restrict__ kl,
    const u16* __restrict__ v_t, u16* __restrict__ y)
{
    __shared__ __align__(16) u16 qls[64 * 40];
    __shared__ __align__(16) u16 kls[128 * 40];
    __shared__ __align__(16) u16 vsT[64 * 136];
    __shared__ __align__(16) u16 Ps [64 * 144];

    const int tid  = threadIdx.x;
    const int lane = tid & 63;
    const int w    = tid >> 6;
    const int n16  = lane & 15;
    const int q4   = lane >> 4;
    const int bh   = blockIdx.x;
    const int qt   = 31 - (int)blockIdx.y;   // heavy q-tiles first
    const int t0   = qt * 64;
    const int nt   = (qt + 2) >> 1;          // # of 128-wide s-tiles

    {
        const int r = tid >> 2, ch = tid & 3;
        uint4 x = *(const uint4*)(ql + ((size_t)bh * T_ + t0 + r) * R_ + ch*8);
        *(uint4*)&qls[r * 40 + ch*8] = x;
    }
    bhalf8 aq = *(const bhalf8*)&qls[(w*16 + n16) * 40 + q4*8];

    const u16* klb = kl  + (size_t)bh * T_ * R_;
    const u16* vtb = v_t + (size_t)bh * DH_ * T_;
    const int rk = tid >> 2, ck = (tid & 3) * 8;
    const int dv = tid >> 4, cv = (tid & 15) * 8;

    uint4 kc0 = *(const uint4*)(klb + (size_t)(rk     ) * R_ + ck);
    uint4 kc1 = *(const uint4*)(klb + (size_t)(rk + 64) * R_ + ck);
    uint4 vc0 = *(const uint4*)(vtb + (size_t)(dv     ) * T_ + cv);
    uint4 vc1 = *(const uint4*)(vtb + (size_t)(dv + 16) * T_ + cv);
    uint4 vc2 = *(const uint4*)(vtb + (size_t)(dv + 32) * T_ + cv);
    uint4 vc3 = *(const uint4*)(vtb + (size_t)(dv + 48) * T_ + cv);
    uint4 kn0 = kc0, kn1 = kc1, vn0 = vc0, vn1 = vc1, vn2 = vc2, vn3 = vc3;

    float m[4], l[4];
    floatx4 O[4];
    #pragma unroll
    for (int r = 0; r < 4; ++r) { m[r] = NEG_; l[r] = 0.f; }
    #pragma unroll
    for (int c = 0; c < 4; ++c) O[c] = (floatx4)(0.f);

    for (int it = 0; it < nt; ++it) {
        const int s0 = it * 128;
        __syncthreads();
        *(uint4*)&kls[(rk     ) * 40 + ck] = kc0;
        *(uint4*)&kls[(rk + 64) * 40 + ck] = kc1;
        *(uint4*)&vsT[(dv     ) * 136 + cv] = vc0;
        *(uint4*)&vsT[(dv + 16) * 136 + cv] = vc1;
        *(uint4*)&vsT[(dv + 32) * 136 + cv] = vc2;
        *(uint4*)&vsT[(dv + 48) * 136 + cv] = vc3;
        if (it + 1 < nt) {
            const int s1 = s0 + 128;
            kn0 = *(const uint4*)(klb + (size_t)(s1 + rk     ) * R_ + ck);
            kn1 = *(const uint4*)(klb + (size_t)(s1 + rk + 64) * R_ + ck);
            vn0 = *(const uint4*)(vtb + (size_t)(dv     ) * T_ + s1 + cv);
            vn1 = *(const uint4*)(vtb + (size_t)(dv + 16) * T_ + s1 + cv);
            vn2 = *(const uint4*)(vtb + (size_t)(dv + 32) * T_ + s1 + cv);
            vn3 = *(const uint4*)(vtb + (size_t)(dv + 48) * T_ + s1 + cv);
        }
        __syncthreads();

        floatx4 Sc[8];
        #pragma unroll
        for (int c = 0; c < 8; ++c) {
            bhalf8 bk = *(const bhalf8*)&kls[(16*c + n16) * 40 + q4*8];
            Sc[c] = __builtin_amdgcn_mfma_f32_16x16x32_bf16(aq, bk, (floatx4)(0.f), 0, 0, 0);
        }

        if (it == nt - 1) {
            const int tg = t0 + w*16 + q4*4;
            #pragma unroll
            for (int c = 0; c < 8; ++c) {
                const int sg = s0 + 16*c + n16;
                #pragma unroll
                for (int r = 0; r < 4; ++r)
                    if (sg > tg + r) Sc[c][r] = NEG_;
            }
        }

        float rmax[4];
        #pragma unroll
        for (int r = 0; r < 4; ++r) {
            float a0 = fmaxf(fmaxf(Sc[0][r], Sc[1][r]), fmaxf(Sc[2][r], Sc[3][r]));
            float a1 = fmaxf(fmaxf(Sc[4][r], Sc[5][r]), fmaxf(Sc[6][r], Sc[7][r]));
            rmax[r] = fmaxf(a0, a1);
        }
        #pragma unroll
        for (int off = 1; off <= 8; off <<= 1)
            #pragma unroll
            for (int r = 0; r < 4; ++r)
                rmax[r] = fmaxf(rmax[r], __shfl_xor(rmax[r], off, 64));

        float alpha[4], rsum[4];
        #pragma unroll
        for (int r = 0; r < 4; ++r) {
            const float mn = fmaxf(m[r], rmax[r]);
            alpha[r] = __expf(m[r] - mn);
            m[r] = mn;
            rsum[r] = 0.f;
        }
        #pragma unroll
        for (int c = 0; c < 8; ++c)
            #pragma unroll
            for (int r = 0; r < 4; ++r) {
                const float p = __expf(Sc[c][r] - m[r]);
                Sc[c][r] = p;
                rsum[r] += p;
            }
        #pragma unroll
        for (int off = 1; off <= 8; off <<= 1)
            #pragma unroll
            for (int r = 0; r < 4; ++r)
                rsum[r] += __shfl_xor(rsum[r], off, 64);
        #pragma unroll
        for (int r = 0; r < 4; ++r) l[r] = l[r] * alpha[r] + rsum[r];
        #pragma unroll
        for (int c = 0; c < 4; ++c)
            #pragma unroll
            for (int r = 0; r < 4; ++r)
                O[c][r] *= alpha[r];

        #pragma unroll
        for (int c = 0; c < 8; ++c)
            #pragma unroll
            for (int r = 0; r < 4; ++r)
                Ps[(w*16 + r*4 + q4) * 144 + 16*c + n16] = tob(Sc[c][r]);

        const int slot = w*16 + (n16 & 3)*4 + (n16 >> 2);
        #pragma unroll
        for (int kc = 0; kc < 4; ++kc) {
            bhalf8 pa = *(const bhalf8*)&Ps[slot * 144 + kc*32 + q4*8];
            #pragma unroll
            for (int c2 = 0; c2 < 4; ++c2) {
                bhalf8 bv = *(const bhalf8*)&vsT[(16*c2 + n16) * 136 + kc*32 + q4*8];
                O[c2] = __builtin_amdgcn_mfma_f32_16x16x32_bf16(pa, bv, O[c2], 0, 0, 0);
            }
        }

        kc0 = kn0; kc1 = kn1; vc0 = vn0; vc1 = vn1; vc2 = vn2; vc3 = vn3;
    }

    const int b = bh >> 4, h = bh & 15;
    #pragma unroll
    for (int r = 0; r < 4; ++r) {
        const float rl = 1.0f / l[r];
        const int t = t0 + w*16 + q4*4 + r;
        #pragma unroll
        for (int c2 = 0; c2 < 4; ++c2)
            y[((size_t)b * T_ + t) * D_ + h * DH_ + 16*c2 + n16] = tob(O[c2][r] * rl);
    }
}

// ---------------------------------------------------------------------------
// Kernel 3: MFMA out-gemm  yb(4096,1024) @ WoT^T -> out fp32 (4096,1024).
// ---------------------------------------------------------------------------
__global__ __launch_bounds__(256) void out_gemm_mfma(
    const u16* __restrict__ yb, const u16* __restrict__ WoT,
    float* __restrict__ out)
{
    __shared__ __align__(16) u16 As[128 * 72];
    __shared__ __align__(16) u16 Bs[128 * 72];
    const int tid  = threadIdx.x;
    const int lane = tid & 63;
    const int w    = tid >> 6;
    const int n16  = lane & 15;
    const int q4   = lane >> 4;
    const int wx   = w & 1;
    const int wy   = w >> 1;
    const int bm   = blockIdx.y * 128;
    const int bn   = blockIdx.x * 128;

    floatx4 acc[4][4];
    #pragma unroll
    for (int i = 0; i < 4; ++i)
        #pragma unroll
        for (int j = 0; j < 4; ++j) acc[i][j] = (floatx4)(0.f);

    for (int kt = 0; kt < D_; kt += 64) {
        #pragma unroll
        for (int p = 0; p < 4; ++p) {
            const int e = tid + p * 256;
            const int r = e >> 3, ch = e & 7;
            uint4 wa = *(const uint4*)(yb  + (size_t)(bm + r) * D_ + kt + ch*8);
            uint4 wb = *(const uint4*)(WoT + (size_t)(bn + r) * D_ + kt + ch*8);
            *(uint4*)&As[r * 72 + ch*8] = wa;
            *(uint4*)&Bs[r * 72 + ch*8] = wb;
        }
        __syncthreads();
        #pragma unroll
        for (int kk = 0; kk < 2; ++kk) {
            bhalf8 a[4], b[4];
            #pragma unroll
            for (int mi = 0; mi < 4; ++mi)
                a[mi] = *(const bhalf8*)&As[(wy*64 + mi*16 + n16) * 72 + kk*32 + q4*8];
            #pragma unroll
            for (int ni = 0; ni < 4; ++ni)
                b[ni] = *(const bhalf8*)&Bs[(wx*64 + ni*16 + n16) * 72 + kk*32 + q4*8];
            #pragma unroll
            for (int mi = 0; mi < 4; ++mi)
                #pragma unroll
                for (int ni = 0; ni < 4; ++ni)
                    acc[mi][ni] = __builtin_amdgcn_mfma_f32_16x16x32_bf16(
                        a[mi], b[ni], acc[mi][ni], 0, 0, 0);
        }
        __syncthreads();
    }

    #pragma unroll
    for (int mi = 0; mi < 4; ++mi) {
        #pragma unroll
        for (int rr = 0; rr < 4; ++rr) {
            const int row = bm + wy*64 + mi*16 + q4*4 + rr;
            #pragma unroll
            for (int ni = 0; ni < 4; ++ni) {
                const int col = bn + wx*64 + ni*16 + n16;
                out[(size_t)row * D_ + col] = acc[mi][ni][rr];
            }
        }
    }
}

// ---------------------------------------------------------------------------
extern "C" void kernel_launch(void* const* d_in, const int* in_sizes, int n_in,
                              void* d_out, int out_size, void* d_ws, size_t ws_size,
                              hipStream_t stream)
{
    (void)out_size; (void)ws_size;
    const void* in_x = nullptr; const void* in_wqkv = nullptr;
    const void* in_wq = nullptr; const void* in_wk = nullptr;
    const void* in_core = nullptr; const void* in_wo = nullptr;
    for (int i = 0; i < n_in; ++i) {
        const int s = in_sizes[i];
        if      (s == BT_*D_)     { if (!in_x)    in_x    = d_in[i]; }
        else if (s == D_*3*D_)    { if (!in_wqkv) in_wqkv = d_in[i]; }
        else if (s == H_*DH_*R_)  { if (!in_wq)   in_wq   = d_in[i]; else if (!in_wk) in_wk = d_in[i]; }
        else if (s == H_*R_)      { if (!in_core) in_core = d_in[i]; }
        else if (s == D_*D_)      { if (!in_wo)   in_wo   = d_in[i]; }
    }
    if (!in_x)    in_x    = d_in[0];
    if (!in_wqkv) in_wqkv = d_in[1];
    if (!in_wq)   in_wq   = d_in[2];
    if (!in_wk)   in_wk   = d_in[3];
    if (!in_core) in_core = d_in[4];
    if (!in_wo)   in_wo   = d_in[5];

    float* out = (float*)d_out;

    char* ws    = (char*)d_ws;
    int*  flag  = (int*)(ws + WSB_FLAG);
    u16*  WcatT = (u16*)(ws + WSB_WCATT);
    u16*  ql    = (u16*)(ws + WSB_QL);
    u16*  kl    = (u16*)(ws + WSB_KL);
    u16*  v_t   = (u16*)(ws + WSB_VT);
    u16*  yb    = (u16*)(ws + WSB_YB);
    u16*  WoT   = (u16*)(ws + WSB_WOT);

    detect_dtype<<<1, 64, 0, stream>>>((const u32*)in_x, flag);
    fold_mfma<<<dim3(8, 16), 256, 0, stream>>>(in_wqkv, in_wq, in_wk, in_core, WcatT, flag);
    convert_T<<<dim3(16,16), 256, 0, stream>>>(in_wqkv, WcatT, 3*D_, 2*D_, 1024, flag); // W_v
    convert_T<<<dim3(16,16), 256, 0, stream>>>(in_wo,   WoT,   D_,   0,    0,    flag); // W_o
    gemm1_mfma<<<dim3(16, 32), 256, 0, stream>>>(in_x, WcatT, ql, kl, v_t, flag);
    attn_kernel<<<dim3(32, 32), 256, 0, stream>>>(ql, kl, v_t, yb);
    out_gemm_mfma<<<dim3(8, 32), 256, 0, stream>>>(yb, WoT, out);
}